// Round 2
// baseline (1573.880 us; speedup 1.0000x reference)
//
#include <hip/hip_runtime.h>
#include <math.h>

namespace {

constexpr int BSZ  = 1024;
constexpr int P    = 128;
constexpr int HG   = 128;
constexpr int NH   = 4;
constexpr int N    = 168;     // P + IND
constexpr int NPAD = 176;     // padded token count (11 tiles of 16)

typedef short bf16x8 __attribute__((ext_vector_type(8)));
typedef float f32x4  __attribute__((ext_vector_type(4)));

__device__ __forceinline__ unsigned short f2bf(float x){
  union { float f; unsigned u; } v; v.f = x;
  unsigned r = (v.u + 0x7FFF + ((v.u >> 16) & 1)) >> 16;
  return (unsigned short)r;
}
__device__ __forceinline__ float bf2f(unsigned short b){
  union { unsigned u; float f; } v; v.u = ((unsigned)b) << 16;
  return v.f;
}

// ---------- wave (64-lane) butterfly reductions: result in ALL lanes ----------
__device__ __forceinline__ float wsum(float v){
  #pragma unroll
  for (int o = 1; o < 64; o <<= 1) v += __shfl_xor(v, o, 64);
  return v;
}
__device__ __forceinline__ float wmax(float v){
  #pragma unroll
  for (int o = 1; o < 64; o <<= 1) v = fmaxf(v, __shfl_xor(v, o, 64));
  return v;
}
__device__ __forceinline__ float wmin(float v){
  #pragma unroll
  for (int o = 1; o < 64; o <<= 1) v = fminf(v, __shfl_xor(v, o, 64));
  return v;
}
__device__ __forceinline__ float rsum256(float v, volatile float* red4){
  #pragma unroll
  for (int o = 32; o > 0; o >>= 1) v += __shfl_down(v, o, 64);
  __syncthreads();
  if ((threadIdx.x & 63) == 0) red4[threadIdx.x >> 6] = v;
  __syncthreads();
  return red4[0] + red4[1] + red4[2] + red4[3];
}

// ---------- K1: per-patch features, one WAVE per patch, no LDS, no barriers ----------
__global__ __launch_bounds__(256) void feat_kernel(const float* __restrict__ X,
                                                   float* __restrict__ Xf){
  const int wave = threadIdx.x >> 6, l = threadIdx.x & 63;
  const int pp = blockIdx.x * 4 + wave;          // patch id
  const float* xp = X + (size_t)pp * 128;
  const float x0 = xp[l];
  const float x1 = xp[l + 64];

  // ---- temporal ----
  float sum   = wsum(x0 + x1);
  float mean  = sum * (1.0f / 128.0f);
  float mx    = wmax(fmaxf(x0, x1));
  float mn    = wmin(fminf(x0, x1));
  float sumsq = wsum(fmaf(x0, x0, x1 * x1));
  float c0 = x0 - mean, c1_ = x1 - mean;
  float c0q = c0 * c0, c1q = c1_ * c1_;
  float m2 = wsum(c0q + c1q);
  float m3 = wsum(c0q * c0 + c1q * c1_);
  float m4 = wsum(c0q * c0q + c1q * c1q);
  float var = m2 * (1.0f / 127.0f);
  float sd  = sqrtf(var);
  float rms = sqrtf(sumsq * (1.0f / 128.0f));
  float ex0 = expf(x0 - mx), ex1 = expf(x1 - mx);
  float Z   = wsum(ex0 + ex1);
  float SxE = wsum(fmaf(ex0, x0, ex1 * x1));
  float ent = (mx + logf(Z)) - SxE / Z;
  const float lo = (float)(-1.0 + 1e-7), hi = (float)(1.0 - 1e-7);
  float a0 = asinf(fminf(fmaxf(x0, lo), hi));
  float a1 = asinf(fminf(fmaxf(x1, lo), hi));
  float amean = wsum(a0 + a1) * (1.0f / 128.0f);
  float ad0 = a0 - amean, ad1 = a1 - amean;
  float std_asin = sqrtf(wsum(fmaf(ad0, ad0, ad1 * ad1)) * (1.0f / 127.0f));
  float b0 = atanf(x0), b1v = atanf(x1);
  float bmean = wsum(b0 + b1v) * (1.0f / 128.0f);
  float bd0 = b0 - bmean, bd1 = b1v - bmean;
  float std_atan = sqrtf(wsum(fmaf(bd0, bd0, bd1 * bd1)) * (1.0f / 127.0f));
  float kurt = (m4 * (1.0f / 128.0f)) / (sd * sd * sd * sd) - 3.0f;
  float skew = (m3 * (1.0f / 128.0f)) / (sd * sd * sd);

  // ---- DFT: lane l computes bin l via rotation recurrence (64 folded steps) ----
  const float sign = (l & 1) ? -1.0f : 1.0f;
  float sC, cC;
  __sincosf((float)l * 0.049087385212340517f, &sC, &cC);   // 2*pi*l/128
  const float c1r = cC, s1r = -sC;
  const int x0i = __float_as_int(x0), x1i = __float_as_int(x1);
  float re = 0.f, im = 0.f;
  float wc = 1.f, ws = 0.f;
  #pragma unroll 8
  for (int tt = 0; tt < 32; ++tt){
    float s0v = __int_as_float(__builtin_amdgcn_readlane(x0i, tt));
    float s1v = __int_as_float(__builtin_amdgcn_readlane(x1i, tt));
    float se = fmaf(sign, s1v, s0v);
    re = fmaf(se, wc, re);
    im = fmaf(se, ws, im);
    float t1 = ws * s1r, t2 = ws * c1r;
    float nwc = fmaf(wc, c1r, -t1);
    ws = fmaf(wc, s1r, t2);
    wc = nwc;
  }
  { // exact reseed at tt=32: w = e^{-i*pi*l/2}
    int lm = l & 3;
    wc = (lm == 0) ? 1.f : (lm == 2) ? -1.f : 0.f;
    ws = (lm == 1) ? -1.f : (lm == 3) ? 1.f : 0.f;
  }
  #pragma unroll 8
  for (int tt = 32; tt < 64; ++tt){
    float s0v = __int_as_float(__builtin_amdgcn_readlane(x0i, tt));
    float s1v = __int_as_float(__builtin_amdgcn_readlane(x1i, tt));
    float se = fmaf(sign, s1v, s0v);
    re = fmaf(se, wc, re);
    im = fmaf(se, ws, im);
    float t1 = ws * s1r, t2 = ws * c1r;
    float nwc = fmaf(wc, c1r, -t1);
    ws = fmaf(wc, s1r, t2);
    wc = nwc;
  }
  float psd = fmaf(re, re, im * im) * 0.0078125f;          // bins 0..63 (lane l)
  float re64 = wsum(sign * (x0 + x1));                     // bin 64
  float psd64 = re64 * re64 * 0.0078125f;

  const float mult = (l == 0) ? 1.f : 2.f;
  float psum = wsum(psd * mult) + psd64;
  float p2   = wsum(psd * psd * mult) + psd64 * psd64;
  float vm   = wmax(psd);
  float maxp = fmaxf(vm, psd64);
  float meanfreq = (-0.5f * psd64) / psum;
  float pbw = sqrtf(p2 / psum);
  float cand = (psd == vm) ? (float)l : 1e9f;              // first-index argmax
  float lminf = wmin(cand);
  float fmaxv = (psd64 > vm) ? -0.5f : lminf * (1.0f / 128.0f);
  float maxamp = sqrtf(maxp * 128.0f);

  // ---- median (stable rank 64 of 128, multiplicity-aware ballot rank) ----
  float med = -0.5f;
  for (int kt = 0; kt < 64; ++kt){
    float vt = __int_as_float(__builtin_amdgcn_readlane(__float_as_int(psd), kt));
    unsigned long long mask = __ballot(psd < vt);
    int less = 2 * __popcll(mask) - (int)(mask & 1ull) + ((psd64 < vt) ? 1 : 0);
    if (less == 64) med = (float)kt * (1.0f / 128.0f);
    else if (less == 63 && kt >= 1) med = -(float)kt * (1.0f / 128.0f);
  }
  {
    unsigned long long mask = __ballot(psd < psd64);
    int less = 2 * __popcll(mask) - (int)(mask & 1ull);
    if (less == 64) med = -0.5f;
  }

  if (l == 0){
    float* o = Xf + (size_t)pp * 40;
    o[0]  = mx;  o[1]  = mn;  o[2]  = sd;   o[3]  = rms; o[4]  = mean;
    o[5]  = mx - mn;  o[6] = var;  o[7] = ent; o[8] = std_asin; o[9] = std_atan;
    o[10] = kurt; o[11] = skew;
    o[12] = meanfreq;
    o[13] = med;
    o[14] = psum;
    o[15] = 1.0f;
    o[16] = pbw;
    o[17] = maxp;
    o[18] = maxamp;
    o[19] = fmaxv;
  }
}

// ---------- K2: cumsum feature + per-sample normalization ----------
__global__ __launch_bounds__(256) void cumnorm_kernel(float* __restrict__ Xf){
  const int b = blockIdx.x, t = threadIdx.x;
  __shared__ float arr[128 * 40];
  __shared__ float red4[4];
  float* base = Xf + b * 5120;
  for (int idx = t; idx < 128 * 20; idx += 256){
    int p = idx / 20, c = idx - p * 20;
    arr[p * 40 + c] = base[p * 40 + c];
  }
  __syncthreads();
  if (t < 20){
    float acc = 0.f;
    for (int p = 0; p < 128; ++p){
      acc += arr[p * 40 + t];
      arr[p * 40 + 20 + t] = acc / sqrtf(fmaxf(fabsf(acc), 1e-12f));
    }
  }
  __syncthreads();
  float pa = 0.f;
  for (int idx = t; idx < 5120; idx += 256){ float v = arr[idx]; pa = fmaf(v, v, pa); }
  float nrm = sqrtf(rsum256(pa, red4));
  for (int idx = t; idx < 5120; idx += 256) base[idx] = arr[idx] / nrm;
}

// ---------- K3: A_t (register-tiled fp32; K-order per output unchanged) ----------
__global__ __launch_bounds__(256) void adjt_kernel(const float* __restrict__ Xf,
    const float* __restrict__ w1, const float* __restrict__ b1,
    const float* __restrict__ w2, const float* __restrict__ b2,
    float* __restrict__ At){
  const int b = blockIdx.x, t = threadIdx.x;
  __shared__ float xf[5120];          // stride 40
  __shared__ float T[128 * 64];
  const float* src = Xf + b * 5120;
  for (int idx = t; idx < 1280; idx += 256)
    *((float4*)xf + idx) = *((const float4*)src + idx);
  __syncthreads();

  // T1[i][k] = tanh(b1[k] + sum_c xf[i][c]*w1[c][k]); tile 8i x 4k per thread
  {
    const int k0 = (t & 15) * 4, i0 = (t >> 4) * 8;
    float4 bv = *(const float4*)&b1[k0];
    float acc[8][4];
    #pragma unroll
    for (int di = 0; di < 8; ++di){ acc[di][0]=bv.x; acc[di][1]=bv.y; acc[di][2]=bv.z; acc[di][3]=bv.w; }
    for (int c = 0; c < 40; ++c){
      float4 wv = *(const float4*)&w1[c * 64 + k0];
      #pragma unroll
      for (int di = 0; di < 8; ++di){
        float xv = xf[(i0 + di) * 40 + c];
        acc[di][0] = fmaf(xv, wv.x, acc[di][0]);
        acc[di][1] = fmaf(xv, wv.y, acc[di][1]);
        acc[di][2] = fmaf(xv, wv.z, acc[di][2]);
        acc[di][3] = fmaf(xv, wv.w, acc[di][3]);
      }
    }
    #pragma unroll
    for (int di = 0; di < 8; ++di){
      float4 o;
      o.x = tanhf(acc[di][0]); o.y = tanhf(acc[di][1]);
      o.z = tanhf(acc[di][2]); o.w = tanhf(acc[di][3]);
      *(float4*)&T[(i0 + di) * 64 + k0] = o;
    }
  }
  __syncthreads();

  // A_t[i][j] = b2[j] + sum_k T[i][k]*w2[k][j]; tile 16i x 4j per thread
  {
    const int j0 = (t & 31) * 4, i0 = (t >> 5) * 16;
    float4 bv = *(const float4*)&b2[j0];
    float acc[16][4];
    #pragma unroll
    for (int di = 0; di < 16; ++di){ acc[di][0]=bv.x; acc[di][1]=bv.y; acc[di][2]=bv.z; acc[di][3]=bv.w; }
    for (int k = 0; k < 64; ++k){
      float4 wv = *(const float4*)&w2[k * 128 + j0];
      #pragma unroll
      for (int di = 0; di < 16; ++di){
        float tv = T[(i0 + di) * 64 + k];
        acc[di][0] = fmaf(tv, wv.x, acc[di][0]);
        acc[di][1] = fmaf(tv, wv.y, acc[di][1]);
        acc[di][2] = fmaf(tv, wv.z, acc[di][2]);
        acc[di][3] = fmaf(tv, wv.w, acc[di][3]);
      }
    }
    float* dst = At + (size_t)b * 16384;
    #pragma unroll
    for (int di = 0; di < 16; ++di)
      *(float4*)&dst[(i0 + di) * 128 + j0] = *(float4*)acc[di];
  }
}

// ---------- K4: A_s ----------
__global__ __launch_bounds__(256) void adjs_kernel(const float* __restrict__ Xf,
    const float* __restrict__ w1, const float* __restrict__ b1,
    const float* __restrict__ w2, const float* __restrict__ b2,
    float* __restrict__ As){
  const int b = blockIdx.x, t = threadIdx.x;
  __shared__ float xf[5120];
  __shared__ float T2[40 * 64];
  const float* src = Xf + b * 5120;
  for (int idx = t; idx < 1280; idx += 256)
    *((float4*)xf + idx) = *((const float4*)src + idx);
  __syncthreads();
  for (int idx = t; idx < 40 * 64; idx += 256){
    int i = idx >> 6, k = idx & 63;
    float acc = b1[k];
    for (int p = 0; p < 128; ++p) acc = fmaf(xf[p * 40 + i], w1[p * 64 + k], acc);
    T2[idx] = tanhf(acc);
  }
  __syncthreads();
  float* dst = As + b * 1600;
  for (int idx = t; idx < 1600; idx += 256){
    int i = idx / 40, j = idx - i * 40;
    float acc = b2[j];
    #pragma unroll 8
    for (int k = 0; k < 64; ++k) acc = fmaf(T2[i * 64 + k], w2[k * 40 + j], acc);
    dst[idx] = acc;
  }
}

// ---------- K5: H_s (register-tiled) ----------
__global__ __launch_bounds__(256) void hs_kernel(const float* __restrict__ Xf,
    const float* __restrict__ As_g, const float* __restrict__ w, const float* __restrict__ bias,
    float* __restrict__ H){
  const int b = blockIdx.x, t = threadIdx.x;
  __shared__ float xf[5120];          // stride 40
  __shared__ float As[1600];
  __shared__ float M[40 * 128];
  const float* src = Xf + b * 5120;
  for (int idx = t; idx < 1280; idx += 256)
    *((float4*)xf + idx) = *((const float4*)src + idx);
  for (int idx = t; idx < 400; idx += 256)
    *((float4*)As + idx) = *((const float4*)(As_g + b * 1600) + idx);
  __syncthreads();

  // M[i][p] = sum_m As[i][m] * xf[p][m]; tile 5i x 4p, m in float4 steps
  {
    const int p0 = (t & 31) * 4, i0 = (t >> 5) * 5;
    float acc[5][4];
    #pragma unroll
    for (int di = 0; di < 5; ++di)
      #pragma unroll
      for (int dp = 0; dp < 4; ++dp) acc[di][dp] = 0.f;
    for (int m = 0; m < 40; m += 4){
      float4 a4[5], x4[4];
      #pragma unroll
      for (int di = 0; di < 5; ++di) a4[di] = *(const float4*)&As[(i0 + di) * 40 + m];
      #pragma unroll
      for (int dp = 0; dp < 4; ++dp) x4[dp] = *(const float4*)&xf[(p0 + dp) * 40 + m];
      #pragma unroll
      for (int dm = 0; dm < 4; ++dm)
        #pragma unroll
        for (int di = 0; di < 5; ++di){
          float av = (&a4[di].x)[dm];
          #pragma unroll
          for (int dp = 0; dp < 4; ++dp)
            acc[di][dp] = fmaf(av, (&x4[dp].x)[dm], acc[di][dp]);
        }
    }
    #pragma unroll
    for (int di = 0; di < 5; ++di)
      *(float4*)&M[(i0 + di) * 128 + p0] = *(float4*)acc[di];
  }
  __syncthreads();

  // H_s[i][j] = leaky(bias[j] + sum_p M[i][p]*w[p][j]); tile 5i x 4j
  {
    const int j0 = (t & 31) * 4, i0 = (t >> 5) * 5;
    float4 bv = *(const float4*)&bias[j0];
    float acc[5][4];
    #pragma unroll
    for (int di = 0; di < 5; ++di){ acc[di][0]=bv.x; acc[di][1]=bv.y; acc[di][2]=bv.z; acc[di][3]=bv.w; }
    for (int p = 0; p < 128; ++p){
      float4 wv = *(const float4*)&w[p * 128 + j0];
      #pragma unroll
      for (int di = 0; di < 5; ++di){
        float mv = M[(i0 + di) * 128 + p];
        acc[di][0] = fmaf(mv, wv.x, acc[di][0]);
        acc[di][1] = fmaf(mv, wv.y, acc[di][1]);
        acc[di][2] = fmaf(mv, wv.z, acc[di][2]);
        acc[di][3] = fmaf(mv, wv.w, acc[di][3]);
      }
    }
    float* dst = H + (size_t)b * (N * HG);
    #pragma unroll
    for (int di = 0; di < 5; ++di){
      float4 o;
      o.x = (acc[di][0] >= 0.f) ? acc[di][0] : 0.01f * acc[di][0];
      o.y = (acc[di][1] >= 0.f) ? acc[di][1] : 0.01f * acc[di][1];
      o.z = (acc[di][2] >= 0.f) ? acc[di][2] : 0.01f * acc[di][2];
      o.w = (acc[di][3] >= 0.f) ? acc[di][3] : 0.01f * acc[di][3];
      *(float4*)&dst[(i0 + di) * 128 + j0] = o;
    }
  }
}

// ---------- K6: H_t (register-tiled) ----------
__global__ __launch_bounds__(256) void ht_kernel(const float* __restrict__ Xf,
    const float* __restrict__ At_g, const float* __restrict__ w, const float* __restrict__ bias,
    float* __restrict__ H){
  const int b = blockIdx.x, t = threadIdx.x;
  __shared__ float xf[5120];          // stride 40
  __shared__ float M2[128 * 40];
  const float* src = Xf + b * 5120;
  for (int idx = t; idx < 1280; idx += 256)
    *((float4*)xf + idx) = *((const float4*)src + idx);
  __syncthreads();

  // M2[i][c] = sum_m At[i][m] * xf[m][c]; tile 4i x 5c, m in float4 steps
  {
    const int c0 = (t & 7) * 5, i0 = (t >> 3) * 4;
    const float* At = At_g + (size_t)b * 16384;
    float acc[4][5];
    #pragma unroll
    for (int di = 0; di < 4; ++di)
      #pragma unroll
      for (int dc = 0; dc < 5; ++dc) acc[di][dc] = 0.f;
    for (int m = 0; m < 128; m += 4){
      float4 a4[4];
      #pragma unroll
      for (int di = 0; di < 4; ++di) a4[di] = *(const float4*)&At[(i0 + di) * 128 + m];
      #pragma unroll
      for (int dm = 0; dm < 4; ++dm){
        float xv[5];
        #pragma unroll
        for (int dc = 0; dc < 5; ++dc) xv[dc] = xf[(m + dm) * 40 + c0 + dc];
        #pragma unroll
        for (int di = 0; di < 4; ++di){
          float av = (&a4[di].x)[dm];
          #pragma unroll
          for (int dc = 0; dc < 5; ++dc)
            acc[di][dc] = fmaf(av, xv[dc], acc[di][dc]);
        }
      }
    }
    #pragma unroll
    for (int di = 0; di < 4; ++di)
      #pragma unroll
      for (int dc = 0; dc < 5; ++dc)
        M2[(i0 + di) * 40 + c0 + dc] = acc[di][dc];
  }
  __syncthreads();

  // H_t[i][j] = leaky(bias[j] + sum_c M2[i][c]*w[c][j]); tile 16i x 4j
  {
    const int j0 = (t & 31) * 4, i0 = (t >> 5) * 16;
    float4 bv = *(const float4*)&bias[j0];
    float acc[16][4];
    #pragma unroll
    for (int di = 0; di < 16; ++di){ acc[di][0]=bv.x; acc[di][1]=bv.y; acc[di][2]=bv.z; acc[di][3]=bv.w; }
    for (int c = 0; c < 40; ++c){
      float4 wv = *(const float4*)&w[c * 128 + j0];
      #pragma unroll
      for (int di = 0; di < 16; ++di){
        float mv = M2[(i0 + di) * 40 + c];
        acc[di][0] = fmaf(mv, wv.x, acc[di][0]);
        acc[di][1] = fmaf(mv, wv.y, acc[di][1]);
        acc[di][2] = fmaf(mv, wv.z, acc[di][2]);
        acc[di][3] = fmaf(mv, wv.w, acc[di][3]);
      }
    }
    float* dst = H + (size_t)b * (N * HG) + 40 * 128;
    #pragma unroll
    for (int di = 0; di < 16; ++di){
      float4 o;
      o.x = (acc[di][0] >= 0.f) ? acc[di][0] : 0.01f * acc[di][0];
      o.y = (acc[di][1] >= 0.f) ? acc[di][1] : 0.01f * acc[di][1];
      o.z = (acc[di][2] >= 0.f) ? acc[di][2] : 0.01f * acc[di][2];
      o.w = (acc[di][3] >= 0.f) ? acc[di][3] : 0.01f * acc[di][3];
      *(float4*)&dst[(i0 + di) * 128 + j0] = o;
    }
  }
}

// out[b] = fc_b + sum_h c4[h]  (c4 = vb-term collapsed: rows of P sum to 1)
__global__ void initout_kernel(float* __restrict__ out, const float* __restrict__ fcb,
                               const float* __restrict__ c4){
  int i = blockIdx.x * 256 + threadIdx.x;
  float base = fcb[0] + c4[0] + c4[1] + c4[2] + c4[3];
  if (i < BSZ) out[i] = base;
}

// ---------- prep: per-head M^T, R = fcw·Wv^T, c1/c2/c3/c4; grid (NH, 11) ----------
// R[h][n][d] = sum_e fcw[n*512+h*128+e] * vw[h][d][e]  (b-independent!)
// c4[h] = sum_{n<168} sum_e vb[h][e] * fcw[n*512+h*128+e]
__global__ __launch_bounds__(256) void prep_kernel(
    const float* __restrict__ qw, const float* __restrict__ qb,
    const float* __restrict__ kw, const float* __restrict__ kb,
    const float* __restrict__ vw, const float* __restrict__ vb,
    const float* __restrict__ fcw,
    short* __restrict__ MT, short* __restrict__ Rbf,
    float* __restrict__ c1, float* __restrict__ c2,
    float* __restrict__ c3, float* __restrict__ c4){
  const int h = blockIdx.x, sl = blockIdx.y, t = threadIdx.x;
  const float* Q = qw + h * 16384;
  const float* K = kw + h * 16384;
  const float* V = vw + h * 16384;
  if (sl < 8){
    for (int idx = t; idx < 2048; idx += 256){
      int j = sl * 16 + (idx >> 7), d = idx & 127;
      float acc = 0.f;
      for (int e = 0; e < 128; ++e) acc = fmaf(Q[d * 128 + e], K[j * 128 + e], acc);
      MT[h * 16384 + j * 128 + d] = (short)f2bf(acc);     // MT[j][d] = M[d][j]
    }
    if (t < 16){
      int r = sl * 16 + t;
      float a = 0.f, bsum = 0.f;
      for (int e = 0; e < 128; ++e){
        a    = fmaf(Q[r * 128 + e], kb[h * 128 + e], a);
        bsum = fmaf(K[r * 128 + e], qb[h * 128 + e], bsum);
      }
      c1[h * 128 + r] = a;
      c2[h * 128 + r] = bsum;
    }
  }
  // R rows n in [sl*16, sl*16+16); zero-pad n >= 168
  for (int idx = t; idx < 2048; idx += 256){
    int n = sl * 16 + (idx >> 7), d = idx & 127;
    float acc = 0.f;
    if (n < N){
      const float* fr = fcw + n * 512 + h * 128;
      const float* vr = V + d * 128;
      for (int e = 0; e < 128; ++e) acc = fmaf(fr[e], vr[e], acc);
    }
    Rbf[h * 22528 + n * 128 + d] = (short)f2bf(acc);
  }
  if (sl == 0){
    if (t == 0){
      float a = 0.f;
      for (int e = 0; e < 128; ++e) a = fmaf(qb[h * 128 + e], kb[h * 128 + e], a);
      c3[h] = a;
    }
    if (t >= 64 && t < 128){                  // wave 1: c4 reduction
      int l = t - 64;
      float part = 0.f;
      for (int i = l; i < N * 128; i += 64){
        int n = i >> 7, e = i & 127;
        part = fmaf(fcw[n * 512 + h * 128 + e], vb[h * 128 + e], part);
      }
      part = wsum(part);
      if (l == 0) c4[h] = part;
    }
  }
}

// ---------- cast H -> bf16 with zero-padded rows 168..175 ----------
__global__ __launch_bounds__(256) void cast_kernel(const float* __restrict__ H,
                                                   short* __restrict__ Hbf){
  const int b = blockIdx.x;
  for (int idx = threadIdx.x; idx < NPAD * 128; idx += 256){
    int n = idx >> 7, d = idx & 127;
    float v = (n < N) ? H[((size_t)b * N + n) * 128 + d] : 0.f;
    Hbf[(size_t)b * NPAD * 128 + idx] = (short)f2bf(v);
  }
}

// ---------- u1/u2 precompute: u1[n]=H[n]·c1, u2[n]=H[n]·c2 per (b,h) ----------
__global__ __launch_bounds__(256) void uprep_kernel(const short* __restrict__ Hbf,
    const float* __restrict__ c1, const float* __restrict__ c2,
    float* __restrict__ u1g, float* __restrict__ u2g){
  const int b = blockIdx.x, t = threadIdx.x;
  for (int idx = t; idx < 176 * 4; idx += 256){
    int n = idx >> 2, h = idx & 3;
    const bf16x8* rp = (const bf16x8*)(Hbf + (size_t)b * NPAD * 128 + (size_t)n * 128);
    const float* C1 = c1 + h * 128;
    const float* C2 = c2 + h * 128;
    float a1 = 0.f, a2 = 0.f;
    for (int kk = 0; kk < 16; ++kk){
      bf16x8 v = rp[kk];
      #pragma unroll
      for (int j = 0; j < 8; ++j){
        float hv = bf2f((unsigned short)v[j]);
        a1 = fmaf(hv, C1[kk * 8 + j], a1);
        a2 = fmaf(hv, C2[kk * 8 + j], a2);
      }
    }
    u1g[(size_t)(b * 4 + h) * 176 + n] = a1;
    u2g[(size_t)(b * 4 + h) * 176 + n] = a2;
  }
}

// ---------- attention mega-kernel: grid (b, h, z), z=0..3 row chunks of 48 ----------
// Phases C+D replaced by Phase G via R-contraction:
//   out_n = sum_m P[n,m] * GT[n,m],  GT = R @ H^T  (R precomputed per head).
// B-fragments (Hb rows m) are shared by Phase B and G: loaded once, kept in regs.
// 3 barriers (was 4); no HbT/WvT/fcw in this kernel at all.
__global__ __launch_bounds__(256) void attn_mega(
    const short* __restrict__ Hbf, const short* __restrict__ MT,
    const short* __restrict__ Rbf,
    const float* __restrict__ u1g, const float* __restrict__ u2g,
    const float* __restrict__ c3g, float* __restrict__ out){
  const int b = blockIdx.x, h = blockIdx.y, z = blockIdx.z;
  const int NT = (z < 3) ? 3 : 2;
  const int rows = NT * 16;
  const int rowbase = z * 48;
  const int t = threadIdx.x;
  const int w = t >> 6, l = t & 63, quad = l >> 4, l15 = l & 15;

  __shared__ __align__(16) short Tsh[48 * 128];       // T (XOR-swizzled)
  __shared__ __align__(16) short Ssh[48 * 184 + 16];  // S then P (bf16, stride 184)
  __shared__ float u1s[48];
  __shared__ float u2s[176];
  __shared__ float red4[4];

  const short* Hb  = Hbf + (size_t)b * NPAD * 128;
  const short* MTh = MT + h * 16384;
  const short* Rh  = Rbf + h * 22528;
  const float c3v = c3g[h];
  const float inv = 0.08838834764831845f;   // 1/sqrt(128)

  if (t < 176) u2s[t] = u2g[(size_t)(b * 4 + h) * 176 + t];
  if (t < rows) u1s[t] = u1g[(size_t)(b * 4 + h) * 176 + rowbase + t];

  // ---- prefetch B-fragments (Hb rows m) used by BOTH Phase B and Phase G ----
  bf16x8 BB[3][4];
  #pragma unroll
  for (int mi = 0; mi < 3; ++mi){
    const int mt = (w + mi * 4 < 11) ? (w + mi * 4) : 10;
    #pragma unroll
    for (int kk = 0; kk < 4; ++kk)
      BB[mi][kk] = *(const bf16x8*)(Hb + (size_t)(mt * 16 + l15) * 128 + kk * 32 + quad * 8);
  }

  // ---- Phase A: T = H_rows @ M  (write bf16, XOR-swizzled) ----
  for (int jt = 0; jt < 2; ++jt){
    const int j0 = (w * 2 + jt) * 16;
    bf16x8 B[4];
    #pragma unroll
    for (int kk = 0; kk < 4; ++kk)
      B[kk] = *(const bf16x8*)(MTh + (j0 + l15) * 128 + kk * 32 + quad * 8);
    for (int nt = 0; nt < NT; ++nt){
      f32x4 acc = {0.f, 0.f, 0.f, 0.f};
      __builtin_amdgcn_s_setprio(1);
      #pragma unroll
      for (int kk = 0; kk < 4; ++kk){
        bf16x8 A = *(const bf16x8*)(Hb + (size_t)(rowbase + nt * 16 + l15) * 128 + kk * 32 + quad * 8);
        acc = __builtin_amdgcn_mfma_f32_16x16x32_bf16(A, B[kk], acc, 0, 0, 0);
      }
      __builtin_amdgcn_s_setprio(0);
      const int jcol = j0 + l15, ch = jcol >> 3;
      #pragma unroll
      for (int r = 0; r < 4; ++r){
        int row = nt * 16 + quad * 4 + r;
        Tsh[row * 128 + ((ch ^ (row & 15)) << 3) + (jcol & 7)] = (short)f2bf(acc[r]);
      }
    }
  }

  // ---- prefetch A-fragments for Phase G (R rows n; static per head, L2-hot) ----
  bf16x8 RA[3][4];
  for (int nt = 0; nt < NT; ++nt){
    #pragma unroll
    for (int kk = 0; kk < 4; ++kk)
      RA[nt][kk] = *(const bf16x8*)(Rh + (rowbase + nt * 16 + l15) * 128 + kk * 32 + quad * 8);
  }
  __syncthreads();

  // ---- Phase B: S = T @ H^T (+rank-1 terms), bf16 into Ssh ----
  for (int mi = 0; mi < 3; ++mi){
    const int mt = w + mi * 4;
    if (mt >= 11) break;
    const int m = mt * 16 + l15;
    const float u2v = u2s[m];
    for (int nt = 0; nt < NT; ++nt){
      f32x4 acc = {0.f, 0.f, 0.f, 0.f};
      __builtin_amdgcn_s_setprio(1);
      #pragma unroll
      for (int kk = 0; kk < 4; ++kk){
        int row = nt * 16 + l15;
        bf16x8 A = *(const bf16x8*)(&Tsh[row * 128 + (((kk * 4 + quad) ^ l15) << 3)]);
        acc = __builtin_amdgcn_mfma_f32_16x16x32_bf16(A, BB[mi][kk], acc, 0, 0, 0);
      }
      __builtin_amdgcn_s_setprio(0);
      #pragma unroll
      for (int r = 0; r < 4; ++r){
        int nl = nt * 16 + quad * 4 + r;
        float s = (acc[r] + u1s[nl] + u2v + c3v) * inv;
        Ssh[nl * 184 + m] = (short)f2bf(s);
      }
    }
  }
  __syncthreads();

  // ---- softmax: one row per wave pass; cols 0..167 valid, 168..175 -> 0 ----
  {
    const int nrw = NT * 4;                 // rows per wave
    for (int rr = 0; rr < nrw; ++rr){
      const int r = w * nrw + rr;
      short* rowp = &Ssh[r * 184];
      float v0 = bf2f((unsigned short)rowp[l]);
      float v1 = bf2f((unsigned short)rowp[64 + l]);
      float v2 = (l < 40) ? bf2f((unsigned short)rowp[128 + l]) : -1e30f;
      float mv = wmax(fmaxf(fmaxf(v0, v1), v2));
      float e0 = __expf(v0 - mv);
      float e1 = __expf(v1 - mv);
      float e2 = (l < 40) ? __expf(v2 - mv) : 0.f;
      float sinv = 1.f / wsum(e0 + e1 + e2);
      rowp[l]      = (short)f2bf(e0 * sinv);
      rowp[64 + l] = (short)f2bf(e1 * sinv);
      if (l < 56) rowp[128 + l] = (l < 40) ? (short)f2bf(e2 * sinv) : (short)0;
    }
  }
  __syncthreads();

  // ---- Phase G: GT = R @ H^T (reuses BB); fused dot with P -> scalar ----
  float tp = 0.f;
  for (int mi = 0; mi < 3; ++mi){
    const int mt = w + mi * 4;
    if (mt >= 11) break;
    const int m0 = mt * 16;
    for (int nt = 0; nt < NT; ++nt){
      f32x4 acc = {0.f, 0.f, 0.f, 0.f};
      __builtin_amdgcn_s_setprio(1);
      #pragma unroll
      for (int kk = 0; kk < 4; ++kk)
        acc = __builtin_amdgcn_mfma_f32_16x16x32_bf16(RA[nt][kk], BB[mi][kk], acc, 0, 0, 0);
      __builtin_amdgcn_s_setprio(0);
      #pragma unroll
      for (int r = 0; r < 4; ++r){
        int nl = nt * 16 + quad * 4 + r;
        if (rowbase + nl < N){
          float pv = bf2f((unsigned short)Ssh[nl * 184 + m0 + l15]);
          tp = fmaf(pv, acc[r], tp);
        }
      }
    }
  }
  float tot = rsum256(tp, red4);
  if (t == 0) atomicAdd(out + b, tot);
}

} // anonymous namespace

extern "C" void kernel_launch(void* const* d_in, const int* in_sizes, int n_in,
                              void* d_out, int out_size, void* d_ws, size_t ws_size,
                              hipStream_t stream) {
  (void)in_sizes; (void)n_in; (void)out_size;
  const float* X      = (const float*)d_in[0];
  const float* spa_w1 = (const float*)d_in[1];
  const float* spa_b1 = (const float*)d_in[2];
  const float* spa_w2 = (const float*)d_in[3];
  const float* spa_b2 = (const float*)d_in[4];
  const float* tem_w1 = (const float*)d_in[5];
  const float* tem_b1 = (const float*)d_in[6];
  const float* tem_w2 = (const float*)d_in[7];
  const float* tem_b2 = (const float*)d_in[8];
  const float* sgnn_w = (const float*)d_in[9];
  const float* sgnn_b = (const float*)d_in[10];
  const float* tgnn_w = (const float*)d_in[11];
  const float* tgnn_b = (const float*)d_in[12];
  const float* q_w    = (const float*)d_in[13];
  const float* q_b    = (const float*)d_in[14];
  const float* k_w    = (const float*)d_in[15];
  const float* k_b    = (const float*)d_in[16];
  const float* v_w    = (const float*)d_in[17];
  const float* v_b    = (const float*)d_in[18];
  const float* fc_w   = (const float*)d_in[19];
  const float* fc_b   = (const float*)d_in[20];
  float* out = (float*)d_out;

  if (ws_size < (size_t)182714368) return;

  char* wsb = (char*)d_ws;
  float* H   = (float*)wsb;                      // fp32 H [0, 88MB)
  float* u1g = (float*)(wsb + 50331648);         // overlays dead-H region (H dead after cast)
  float* u2g = (float*)(wsb + 53215232);
  char*  Rb  = wsb + 88080384;
  float* Xf  = (float*)Rb;
  float* As  = (float*)(Rb + 20971520);
  float* At  = (float*)(Rb + 27525120);
  short* Hbf = (short*)Rb;                       // overlays dead Xf/As/At after ht
  char*  Pb  = Rb + 46137344;
  short* MT  = (short*)Pb;                       // 131072 B
  short* Rbf = (short*)(Pb + 131072);            // 180224 B (4 heads x 176 x 128 bf16)
  float* c1  = (float*)(Pb + 311296);
  float* c2  = (float*)(Pb + 313344);
  float* c3  = (float*)(Pb + 315392);
  float* c4  = (float*)(Pb + 315408);

  feat_kernel<<<BSZ * P / 4, 256, 0, stream>>>(X, Xf);
  cumnorm_kernel<<<BSZ, 256, 0, stream>>>(Xf);
  adjt_kernel<<<BSZ, 256, 0, stream>>>(Xf, tem_w1, tem_b1, tem_w2, tem_b2, At);
  adjs_kernel<<<BSZ, 256, 0, stream>>>(Xf, spa_w1, spa_b1, spa_w2, spa_b2, As);
  hs_kernel<<<BSZ, 256, 0, stream>>>(Xf, As, sgnn_w, sgnn_b, H);
  ht_kernel<<<BSZ, 256, 0, stream>>>(Xf, At, tgnn_w, tgnn_b, H);
  prep_kernel<<<dim3(NH, 11), 256, 0, stream>>>(q_w, q_b, k_w, k_b, v_w, v_b, fc_w,
                                                MT, Rbf, c1, c2, c3, c4);
  cast_kernel<<<BSZ, 256, 0, stream>>>(H, Hbf);          // H fp32 dead after this
  uprep_kernel<<<BSZ, 256, 0, stream>>>(Hbf, c1, c2, u1g, u2g);
  initout_kernel<<<4, 256, 0, stream>>>(out, fc_b, c4);
  attn_mega<<<dim3(BSZ, NH, 4), 256, 0, stream>>>(Hbf, MT, Rbf, u1g, u2g, c3, out);
}

// Round 4
// 1531.047 us; speedup vs baseline: 1.0280x; 1.0280x over previous
//
#include <hip/hip_runtime.h>
#include <math.h>

namespace {

constexpr int BSZ  = 1024;
constexpr int P    = 128;
constexpr int HG   = 128;
constexpr int NH   = 4;
constexpr int N    = 168;     // P + IND
constexpr int NPAD = 176;     // padded token count (11 tiles of 16)

typedef short bf16x8 __attribute__((ext_vector_type(8)));
typedef float f32x4  __attribute__((ext_vector_type(4)));

__device__ __forceinline__ unsigned short f2bf(float x){
  union { float f; unsigned u; } v; v.f = x;
  unsigned r = (v.u + 0x7FFF + ((v.u >> 16) & 1)) >> 16;
  return (unsigned short)r;
}
__device__ __forceinline__ float bf2f(unsigned short b){
  union { unsigned u; float f; } v; v.u = ((unsigned)b) << 16;
  return v.f;
}

// ---------- wave (64-lane) butterfly reductions: result in ALL lanes ----------
__device__ __forceinline__ float wsum(float v){
  #pragma unroll
  for (int o = 1; o < 64; o <<= 1) v += __shfl_xor(v, o, 64);
  return v;
}
__device__ __forceinline__ float wmax(float v){
  #pragma unroll
  for (int o = 1; o < 64; o <<= 1) v = fmaxf(v, __shfl_xor(v, o, 64));
  return v;
}
__device__ __forceinline__ float wmin(float v){
  #pragma unroll
  for (int o = 1; o < 64; o <<= 1) v = fminf(v, __shfl_xor(v, o, 64));
  return v;
}
__device__ __forceinline__ float rsum256(float v, volatile float* red4){
  #pragma unroll
  for (int o = 32; o > 0; o >>= 1) v += __shfl_down(v, o, 64);
  __syncthreads();
  if ((threadIdx.x & 63) == 0) red4[threadIdx.x >> 6] = v;
  __syncthreads();
  return red4[0] + red4[1] + red4[2] + red4[3];
}

// ---------- K1: per-patch features, one WAVE per patch, no LDS, no barriers ----------
__global__ __launch_bounds__(256) void feat_kernel(const float* __restrict__ X,
                                                   float* __restrict__ Xf){
  const int wave = threadIdx.x >> 6, l = threadIdx.x & 63;
  const int pp = blockIdx.x * 4 + wave;          // patch id
  const float* xp = X + (size_t)pp * 128;
  const float x0 = xp[l];
  const float x1 = xp[l + 64];

  // ---- temporal ----
  float sum   = wsum(x0 + x1);
  float mean  = sum * (1.0f / 128.0f);
  float mx    = wmax(fmaxf(x0, x1));
  float mn    = wmin(fminf(x0, x1));
  float sumsq = wsum(fmaf(x0, x0, x1 * x1));
  float c0 = x0 - mean, c1_ = x1 - mean;
  float c0q = c0 * c0, c1q = c1_ * c1_;
  float m2 = wsum(c0q + c1q);
  float m3 = wsum(c0q * c0 + c1q * c1_);
  float m4 = wsum(c0q * c0q + c1q * c1q);
  float var = m2 * (1.0f / 127.0f);
  float sd  = sqrtf(var);
  float rms = sqrtf(sumsq * (1.0f / 128.0f));
  float ex0 = expf(x0 - mx), ex1 = expf(x1 - mx);
  float Z   = wsum(ex0 + ex1);
  float SxE = wsum(fmaf(ex0, x0, ex1 * x1));
  float ent = (mx + logf(Z)) - SxE / Z;
  const float lo = (float)(-1.0 + 1e-7), hi = (float)(1.0 - 1e-7);
  float a0 = asinf(fminf(fmaxf(x0, lo), hi));
  float a1 = asinf(fminf(fmaxf(x1, lo), hi));
  float amean = wsum(a0 + a1) * (1.0f / 128.0f);
  float ad0 = a0 - amean, ad1 = a1 - amean;
  float std_asin = sqrtf(wsum(fmaf(ad0, ad0, ad1 * ad1)) * (1.0f / 127.0f));
  float b0 = atanf(x0), b1v = atanf(x1);
  float bmean = wsum(b0 + b1v) * (1.0f / 128.0f);
  float bd0 = b0 - bmean, bd1 = b1v - bmean;
  float std_atan = sqrtf(wsum(fmaf(bd0, bd0, bd1 * bd1)) * (1.0f / 127.0f));
  float kurt = (m4 * (1.0f / 128.0f)) / (sd * sd * sd * sd) - 3.0f;
  float skew = (m3 * (1.0f / 128.0f)) / (sd * sd * sd);

  // ---- DFT: lane l computes bin l via rotation recurrence (64 folded steps) ----
  const float sign = (l & 1) ? -1.0f : 1.0f;
  float sC, cC;
  __sincosf((float)l * 0.049087385212340517f, &sC, &cC);   // 2*pi*l/128
  const float c1r = cC, s1r = -sC;
  const int x0i = __float_as_int(x0), x1i = __float_as_int(x1);
  float re = 0.f, im = 0.f;
  float wc = 1.f, ws = 0.f;
  #pragma unroll 8
  for (int tt = 0; tt < 32; ++tt){
    float s0v = __int_as_float(__builtin_amdgcn_readlane(x0i, tt));
    float s1v = __int_as_float(__builtin_amdgcn_readlane(x1i, tt));
    float se = fmaf(sign, s1v, s0v);
    re = fmaf(se, wc, re);
    im = fmaf(se, ws, im);
    float t1 = ws * s1r, t2 = ws * c1r;
    float nwc = fmaf(wc, c1r, -t1);
    ws = fmaf(wc, s1r, t2);
    wc = nwc;
  }
  { // exact reseed at tt=32: w = e^{-i*pi*l/2}
    int lm = l & 3;
    wc = (lm == 0) ? 1.f : (lm == 2) ? -1.f : 0.f;
    ws = (lm == 1) ? -1.f : (lm == 3) ? 1.f : 0.f;
  }
  #pragma unroll 8
  for (int tt = 32; tt < 64; ++tt){
    float s0v = __int_as_float(__builtin_amdgcn_readlane(x0i, tt));
    float s1v = __int_as_float(__builtin_amdgcn_readlane(x1i, tt));
    float se = fmaf(sign, s1v, s0v);
    re = fmaf(se, wc, re);
    im = fmaf(se, ws, im);
    float t1 = ws * s1r, t2 = ws * c1r;
    float nwc = fmaf(wc, c1r, -t1);
    ws = fmaf(wc, s1r, t2);
    wc = nwc;
  }
  float psd = fmaf(re, re, im * im) * 0.0078125f;          // bins 0..63 (lane l)
  float re64 = wsum(sign * (x0 + x1));                     // bin 64
  float psd64 = re64 * re64 * 0.0078125f;

  const float mult = (l == 0) ? 1.f : 2.f;
  float psum = wsum(psd * mult) + psd64;
  float p2   = wsum(psd * psd * mult) + psd64 * psd64;
  float vm   = wmax(psd);
  float maxp = fmaxf(vm, psd64);
  float meanfreq = (-0.5f * psd64) / psum;
  float pbw = sqrtf(p2 / psum);
  float cand = (psd == vm) ? (float)l : 1e9f;              // first-index argmax
  float lminf = wmin(cand);
  float fmaxv = (psd64 > vm) ? -0.5f : lminf * (1.0f / 128.0f);
  float maxamp = sqrtf(maxp * 128.0f);

  // ---- median (stable rank 64 of 128, multiplicity-aware ballot rank) ----
  float med = -0.5f;
  for (int kt = 0; kt < 64; ++kt){
    float vt = __int_as_float(__builtin_amdgcn_readlane(__float_as_int(psd), kt));
    unsigned long long mask = __ballot(psd < vt);
    int less = 2 * __popcll(mask) - (int)(mask & 1ull) + ((psd64 < vt) ? 1 : 0);
    if (less == 64) med = (float)kt * (1.0f / 128.0f);
    else if (less == 63 && kt >= 1) med = -(float)kt * (1.0f / 128.0f);
  }
  {
    unsigned long long mask = __ballot(psd < psd64);
    int less = 2 * __popcll(mask) - (int)(mask & 1ull);
    if (less == 64) med = -0.5f;
  }

  if (l == 0){
    float* o = Xf + (size_t)pp * 40;
    o[0]  = mx;  o[1]  = mn;  o[2]  = sd;   o[3]  = rms; o[4]  = mean;
    o[5]  = mx - mn;  o[6] = var;  o[7] = ent; o[8] = std_asin; o[9] = std_atan;
    o[10] = kurt; o[11] = skew;
    o[12] = meanfreq;
    o[13] = med;
    o[14] = psum;
    o[15] = 1.0f;
    o[16] = pbw;
    o[17] = maxp;
    o[18] = maxamp;
    o[19] = fmaxv;
  }
}

// ---------- K2: cumsum feature + per-sample normalization ----------
__global__ __launch_bounds__(256) void cumnorm_kernel(float* __restrict__ Xf){
  const int b = blockIdx.x, t = threadIdx.x;
  __shared__ float arr[128 * 40];
  __shared__ float red4[4];
  float* base = Xf + b * 5120;
  for (int idx = t; idx < 128 * 20; idx += 256){
    int p = idx / 20, c = idx - p * 20;
    arr[p * 40 + c] = base[p * 40 + c];
  }
  __syncthreads();
  if (t < 20){
    float acc = 0.f;
    for (int p = 0; p < 128; ++p){
      acc += arr[p * 40 + t];
      arr[p * 40 + 20 + t] = acc / sqrtf(fmaxf(fabsf(acc), 1e-12f));
    }
  }
  __syncthreads();
  float pa = 0.f;
  for (int idx = t; idx < 5120; idx += 256){ float v = arr[idx]; pa = fmaf(v, v, pa); }
  float nrm = sqrtf(rsum256(pa, red4));
  for (int idx = t; idx < 5120; idx += 256) base[idx] = arr[idx] / nrm;
}

// ---------- K3: A_t (register-tiled fp32; K-order per output unchanged) ----------
__global__ __launch_bounds__(256) void adjt_kernel(const float* __restrict__ Xf,
    const float* __restrict__ w1, const float* __restrict__ b1,
    const float* __restrict__ w2, const float* __restrict__ b2,
    float* __restrict__ At){
  const int b = blockIdx.x, t = threadIdx.x;
  __shared__ float xf[5120];          // stride 40
  __shared__ float T[128 * 64];
  const float* src = Xf + b * 5120;
  for (int idx = t; idx < 1280; idx += 256)
    *((float4*)xf + idx) = *((const float4*)src + idx);
  __syncthreads();

  // T1[i][k] = tanh(b1[k] + sum_c xf[i][c]*w1[c][k]); tile 8i x 4k per thread
  {
    const int k0 = (t & 15) * 4, i0 = (t >> 4) * 8;
    float4 bv = *(const float4*)&b1[k0];
    float acc[8][4];
    #pragma unroll
    for (int di = 0; di < 8; ++di){ acc[di][0]=bv.x; acc[di][1]=bv.y; acc[di][2]=bv.z; acc[di][3]=bv.w; }
    for (int c = 0; c < 40; ++c){
      float4 wv = *(const float4*)&w1[c * 64 + k0];
      #pragma unroll
      for (int di = 0; di < 8; ++di){
        float xv = xf[(i0 + di) * 40 + c];
        acc[di][0] = fmaf(xv, wv.x, acc[di][0]);
        acc[di][1] = fmaf(xv, wv.y, acc[di][1]);
        acc[di][2] = fmaf(xv, wv.z, acc[di][2]);
        acc[di][3] = fmaf(xv, wv.w, acc[di][3]);
      }
    }
    #pragma unroll
    for (int di = 0; di < 8; ++di){
      float4 o;
      o.x = tanhf(acc[di][0]); o.y = tanhf(acc[di][1]);
      o.z = tanhf(acc[di][2]); o.w = tanhf(acc[di][3]);
      *(float4*)&T[(i0 + di) * 64 + k0] = o;
    }
  }
  __syncthreads();

  // A_t[i][j] = b2[j] + sum_k T[i][k]*w2[k][j]; tile 16i x 4j per thread
  {
    const int j0 = (t & 31) * 4, i0 = (t >> 5) * 16;
    float4 bv = *(const float4*)&b2[j0];
    float acc[16][4];
    #pragma unroll
    for (int di = 0; di < 16; ++di){ acc[di][0]=bv.x; acc[di][1]=bv.y; acc[di][2]=bv.z; acc[di][3]=bv.w; }
    for (int k = 0; k < 64; ++k){
      float4 wv = *(const float4*)&w2[k * 128 + j0];
      #pragma unroll
      for (int di = 0; di < 16; ++di){
        float tv = T[(i0 + di) * 64 + k];
        acc[di][0] = fmaf(tv, wv.x, acc[di][0]);
        acc[di][1] = fmaf(tv, wv.y, acc[di][1]);
        acc[di][2] = fmaf(tv, wv.z, acc[di][2]);
        acc[di][3] = fmaf(tv, wv.w, acc[di][3]);
      }
    }
    float* dst = At + (size_t)b * 16384;
    #pragma unroll
    for (int di = 0; di < 16; ++di)
      *(float4*)&dst[(i0 + di) * 128 + j0] = *(float4*)acc[di];
  }
}

// ---------- K4: A_s ----------
__global__ __launch_bounds__(256) void adjs_kernel(const float* __restrict__ Xf,
    const float* __restrict__ w1, const float* __restrict__ b1,
    const float* __restrict__ w2, const float* __restrict__ b2,
    float* __restrict__ As){
  const int b = blockIdx.x, t = threadIdx.x;
  __shared__ float xf[5120];
  __shared__ float T2[40 * 64];
  const float* src = Xf + b * 5120;
  for (int idx = t; idx < 1280; idx += 256)
    *((float4*)xf + idx) = *((const float4*)src + idx);
  __syncthreads();
  for (int idx = t; idx < 40 * 64; idx += 256){
    int i = idx >> 6, k = idx & 63;
    float acc = b1[k];
    for (int p = 0; p < 128; ++p) acc = fmaf(xf[p * 40 + i], w1[p * 64 + k], acc);
    T2[idx] = tanhf(acc);
  }
  __syncthreads();
  float* dst = As + b * 1600;
  for (int idx = t; idx < 1600; idx += 256){
    int i = idx / 40, j = idx - i * 40;
    float acc = b2[j];
    #pragma unroll 8
    for (int k = 0; k < 64; ++k) acc = fmaf(T2[i * 64 + k], w2[k * 40 + j], acc);
    dst[idx] = acc;
  }
}

// ---------- K5: H_s (register-tiled) ----------
__global__ __launch_bounds__(256) void hs_kernel(const float* __restrict__ Xf,
    const float* __restrict__ As_g, const float* __restrict__ w, const float* __restrict__ bias,
    float* __restrict__ H){
  const int b = blockIdx.x, t = threadIdx.x;
  __shared__ float xf[5120];          // stride 40
  __shared__ float As[1600];
  __shared__ float M[40 * 128];
  const float* src = Xf + b * 5120;
  for (int idx = t; idx < 1280; idx += 256)
    *((float4*)xf + idx) = *((const float4*)src + idx);
  for (int idx = t; idx < 400; idx += 256)
    *((float4*)As + idx) = *((const float4*)(As_g + b * 1600) + idx);
  __syncthreads();

  // M[i][p] = sum_m As[i][m] * xf[p][m]; tile 5i x 4p, m in float4 steps
  {
    const int p0 = (t & 31) * 4, i0 = (t >> 5) * 5;
    float acc[5][4];
    #pragma unroll
    for (int di = 0; di < 5; ++di)
      #pragma unroll
      for (int dp = 0; dp < 4; ++dp) acc[di][dp] = 0.f;
    for (int m = 0; m < 40; m += 4){
      float4 a4[5], x4[4];
      #pragma unroll
      for (int di = 0; di < 5; ++di) a4[di] = *(const float4*)&As[(i0 + di) * 40 + m];
      #pragma unroll
      for (int dp = 0; dp < 4; ++dp) x4[dp] = *(const float4*)&xf[(p0 + dp) * 40 + m];
      #pragma unroll
      for (int dm = 0; dm < 4; ++dm)
        #pragma unroll
        for (int di = 0; di < 5; ++di){
          float av = (&a4[di].x)[dm];
          #pragma unroll
          for (int dp = 0; dp < 4; ++dp)
            acc[di][dp] = fmaf(av, (&x4[dp].x)[dm], acc[di][dp]);
        }
    }
    #pragma unroll
    for (int di = 0; di < 5; ++di)
      *(float4*)&M[(i0 + di) * 128 + p0] = *(float4*)acc[di];
  }
  __syncthreads();

  // H_s[i][j] = leaky(bias[j] + sum_p M[i][p]*w[p][j]); tile 5i x 4j
  {
    const int j0 = (t & 31) * 4, i0 = (t >> 5) * 5;
    float4 bv = *(const float4*)&bias[j0];
    float acc[5][4];
    #pragma unroll
    for (int di = 0; di < 5; ++di){ acc[di][0]=bv.x; acc[di][1]=bv.y; acc[di][2]=bv.z; acc[di][3]=bv.w; }
    for (int p = 0; p < 128; ++p){
      float4 wv = *(const float4*)&w[p * 128 + j0];
      #pragma unroll
      for (int di = 0; di < 5; ++di){
        float mv = M[(i0 + di) * 128 + p];
        acc[di][0] = fmaf(mv, wv.x, acc[di][0]);
        acc[di][1] = fmaf(mv, wv.y, acc[di][1]);
        acc[di][2] = fmaf(mv, wv.z, acc[di][2]);
        acc[di][3] = fmaf(mv, wv.w, acc[di][3]);
      }
    }
    float* dst = H + (size_t)b * (N * HG);
    #pragma unroll
    for (int di = 0; di < 5; ++di){
      float4 o;
      o.x = (acc[di][0] >= 0.f) ? acc[di][0] : 0.01f * acc[di][0];
      o.y = (acc[di][1] >= 0.f) ? acc[di][1] : 0.01f * acc[di][1];
      o.z = (acc[di][2] >= 0.f) ? acc[di][2] : 0.01f * acc[di][2];
      o.w = (acc[di][3] >= 0.f) ? acc[di][3] : 0.01f * acc[di][3];
      *(float4*)&dst[(i0 + di) * 128 + j0] = o;
    }
  }
}

// ---------- K6: H_t (register-tiled) ----------
__global__ __launch_bounds__(256) void ht_kernel(const float* __restrict__ Xf,
    const float* __restrict__ At_g, const float* __restrict__ w, const float* __restrict__ bias,
    float* __restrict__ H){
  const int b = blockIdx.x, t = threadIdx.x;
  __shared__ float xf[5120];          // stride 40
  __shared__ float M2[128 * 40];
  const float* src = Xf + b * 5120;
  for (int idx = t; idx < 1280; idx += 256)
    *((float4*)xf + idx) = *((const float4*)src + idx);
  __syncthreads();

  // M2[i][c] = sum_m At[i][m] * xf[m][c]; tile 4i x 5c, m in float4 steps
  {
    const int c0 = (t & 7) * 5, i0 = (t >> 3) * 4;
    const float* At = At_g + (size_t)b * 16384;
    float acc[4][5];
    #pragma unroll
    for (int di = 0; di < 4; ++di)
      #pragma unroll
      for (int dc = 0; dc < 5; ++dc) acc[di][dc] = 0.f;
    for (int m = 0; m < 128; m += 4){
      float4 a4[4];
      #pragma unroll
      for (int di = 0; di < 4; ++di) a4[di] = *(const float4*)&At[(i0 + di) * 128 + m];
      #pragma unroll
      for (int dm = 0; dm < 4; ++dm){
        float xv[5];
        #pragma unroll
        for (int dc = 0; dc < 5; ++dc) xv[dc] = xf[(m + dm) * 40 + c0 + dc];
        #pragma unroll
        for (int di = 0; di < 4; ++di){
          float av = (&a4[di].x)[dm];
          #pragma unroll
          for (int dc = 0; dc < 5; ++dc)
            acc[di][dc] = fmaf(av, xv[dc], acc[di][dc]);
        }
      }
    }
    #pragma unroll
    for (int di = 0; di < 4; ++di)
      #pragma unroll
      for (int dc = 0; dc < 5; ++dc)
        M2[(i0 + di) * 40 + c0 + dc] = acc[di][dc];
  }
  __syncthreads();

  // H_t[i][j] = leaky(bias[j] + sum_c M2[i][c]*w[c][j]); tile 16i x 4j
  {
    const int j0 = (t & 31) * 4, i0 = (t >> 5) * 16;
    float4 bv = *(const float4*)&bias[j0];
    float acc[16][4];
    #pragma unroll
    for (int di = 0; di < 16; ++di){ acc[di][0]=bv.x; acc[di][1]=bv.y; acc[di][2]=bv.z; acc[di][3]=bv.w; }
    for (int c = 0; c < 40; ++c){
      float4 wv = *(const float4*)&w[c * 128 + j0];
      #pragma unroll
      for (int di = 0; di < 16; ++di){
        float mv = M2[(i0 + di) * 40 + c];
        acc[di][0] = fmaf(mv, wv.x, acc[di][0]);
        acc[di][1] = fmaf(mv, wv.y, acc[di][1]);
        acc[di][2] = fmaf(mv, wv.z, acc[di][2]);
        acc[di][3] = fmaf(mv, wv.w, acc[di][3]);
      }
    }
    float* dst = H + (size_t)b * (N * HG) + 40 * 128;
    #pragma unroll
    for (int di = 0; di < 16; ++di){
      float4 o;
      o.x = (acc[di][0] >= 0.f) ? acc[di][0] : 0.01f * acc[di][0];
      o.y = (acc[di][1] >= 0.f) ? acc[di][1] : 0.01f * acc[di][1];
      o.z = (acc[di][2] >= 0.f) ? acc[di][2] : 0.01f * acc[di][2];
      o.w = (acc[di][3] >= 0.f) ? acc[di][3] : 0.01f * acc[di][3];
      *(float4*)&dst[(i0 + di) * 128 + j0] = o;
    }
  }
}

// out[b] = fc_b + sum_h c4[h]  (c4 = vb-term collapsed: rows of P sum to 1)
__global__ void initout_kernel(float* __restrict__ out, const float* __restrict__ fcb,
                               const float* __restrict__ c4){
  int i = blockIdx.x * 256 + threadIdx.x;
  float base = fcb[0] + c4[0] + c4[1] + c4[2] + c4[3];
  if (i < BSZ) out[i] = base;
}

// ---------- prep: per-head M^T, R = fcw·Wv^T, c1/c2/c3/c4; grid (NH, 11) ----------
// R[h][n][d] = sum_e fcw[n*512+h*128+e] * vw[h][d][e]  (b-independent!)
// c4[h] = sum_{n<168} sum_e vb[h][e] * fcw[n*512+h*128+e]
__global__ __launch_bounds__(256) void prep_kernel(
    const float* __restrict__ qw, const float* __restrict__ qb,
    const float* __restrict__ kw, const float* __restrict__ kb,
    const float* __restrict__ vw, const float* __restrict__ vb,
    const float* __restrict__ fcw,
    short* __restrict__ MT, short* __restrict__ Rbf,
    float* __restrict__ c1, float* __restrict__ c2,
    float* __restrict__ c3, float* __restrict__ c4){
  const int h = blockIdx.x, sl = blockIdx.y, t = threadIdx.x;
  const float* Q = qw + h * 16384;
  const float* K = kw + h * 16384;
  const float* V = vw + h * 16384;
  if (sl < 8){
    for (int idx = t; idx < 2048; idx += 256){
      int j = sl * 16 + (idx >> 7), d = idx & 127;
      float acc = 0.f;
      for (int e = 0; e < 128; ++e) acc = fmaf(Q[d * 128 + e], K[j * 128 + e], acc);
      MT[h * 16384 + j * 128 + d] = (short)f2bf(acc);     // MT[j][d] = M[d][j]
    }
    if (t < 16){
      int r = sl * 16 + t;
      float a = 0.f, bsum = 0.f;
      for (int e = 0; e < 128; ++e){
        a    = fmaf(Q[r * 128 + e], kb[h * 128 + e], a);
        bsum = fmaf(K[r * 128 + e], qb[h * 128 + e], bsum);
      }
      c1[h * 128 + r] = a;
      c2[h * 128 + r] = bsum;
    }
  }
  // R rows n in [sl*16, sl*16+16); zero-pad n >= 168
  for (int idx = t; idx < 2048; idx += 256){
    int n = sl * 16 + (idx >> 7), d = idx & 127;
    float acc = 0.f;
    if (n < N){
      const float* fr = fcw + n * 512 + h * 128;
      const float* vr = V + d * 128;
      for (int e = 0; e < 128; ++e) acc = fmaf(fr[e], vr[e], acc);
    }
    Rbf[h * 22528 + n * 128 + d] = (short)f2bf(acc);
  }
  if (sl == 0){
    if (t == 0){
      float a = 0.f;
      for (int e = 0; e < 128; ++e) a = fmaf(qb[h * 128 + e], kb[h * 128 + e], a);
      c3[h] = a;
    }
    if (t >= 64 && t < 128){                  // wave 1: c4 reduction
      int l = t - 64;
      float part = 0.f;
      for (int i = l; i < N * 128; i += 64){
        int n = i >> 7, e = i & 127;
        part = fmaf(fcw[n * 512 + h * 128 + e], vb[h * 128 + e], part);
      }
      part = wsum(part);
      if (l == 0) c4[h] = part;
    }
  }
}

// ---------- cast H -> bf16 with zero-padded rows 168..175 ----------
__global__ __launch_bounds__(256) void cast_kernel(const float* __restrict__ H,
                                                   short* __restrict__ Hbf){
  const int b = blockIdx.x;
  for (int idx = threadIdx.x; idx < NPAD * 128; idx += 256){
    int n = idx >> 7, d = idx & 127;
    float v = (n < N) ? H[((size_t)b * N + n) * 128 + d] : 0.f;
    Hbf[(size_t)b * NPAD * 128 + idx] = (short)f2bf(v);
  }
}

// ---------- u1/u2 precompute: u1[n]=H[n]·c1, u2[n]=H[n]·c2 per (b,h) ----------
__global__ __launch_bounds__(256) void uprep_kernel(const short* __restrict__ Hbf,
    const float* __restrict__ c1, const float* __restrict__ c2,
    float* __restrict__ u1g, float* __restrict__ u2g){
  const int b = blockIdx.x, t = threadIdx.x;
  for (int idx = t; idx < 176 * 4; idx += 256){
    int n = idx >> 2, h = idx & 3;
    const bf16x8* rp = (const bf16x8*)(Hbf + (size_t)b * NPAD * 128 + (size_t)n * 128);
    const float* C1 = c1 + h * 128;
    const float* C2 = c2 + h * 128;
    float a1 = 0.f, a2 = 0.f;
    for (int kk = 0; kk < 16; ++kk){
      bf16x8 v = rp[kk];
      #pragma unroll
      for (int j = 0; j < 8; ++j){
        float hv = bf2f((unsigned short)v[j]);
        a1 = fmaf(hv, C1[kk * 8 + j], a1);
        a2 = fmaf(hv, C2[kk * 8 + j], a2);
      }
    }
    u1g[(size_t)(b * 4 + h) * 176 + n] = a1;
    u2g[(size_t)(b * 4 + h) * 176 + n] = a2;
  }
}

// ---------- attention mega-kernel: grid (b, h, z), z=0..3 row chunks of 48 ----------
// Phase G (out_n = sum_m P[n,m]*GT[n,m], GT = R @ H^T) replaces old C+D.
// ALL MFMA fragments loaded inline in loop bodies (r2's BB[3][4]/RA[3][4] register
// arrays were runtime-indexed -> scratch spill, 721 MB WRITE_SIZE). L1/L2 serve
// the repeated Hb/Rh reads (shared across 16 blocks per b).
__global__ __launch_bounds__(256) void attn_mega(
    const short* __restrict__ Hbf, const short* __restrict__ MT,
    const short* __restrict__ Rbf,
    const float* __restrict__ u1g, const float* __restrict__ u2g,
    const float* __restrict__ c3g, float* __restrict__ out){
  const int b = blockIdx.x, h = blockIdx.y, z = blockIdx.z;
  const int NT = (z < 3) ? 3 : 2;
  const int rows = NT * 16;
  const int rowbase = z * 48;
  const int t = threadIdx.x;
  const int w = t >> 6, l = t & 63, quad = l >> 4, l15 = l & 15;

  __shared__ __align__(16) short Tsh[48 * 128];       // T (XOR-swizzled)
  __shared__ __align__(16) short Ssh[48 * 184 + 16];  // S then P (bf16, stride 184)
  __shared__ float u1s[48];
  __shared__ float u2s[176];
  __shared__ float red4[4];

  const short* Hb  = Hbf + (size_t)b * NPAD * 128;
  const short* MTh = MT + h * 16384;
  const short* Rh  = Rbf + h * 22528;
  const float c3v = c3g[h];
  const float inv = 0.08838834764831845f;   // 1/sqrt(128)

  if (t < 176) u2s[t] = u2g[(size_t)(b * 4 + h) * 176 + t];
  if (t < rows) u1s[t] = u1g[(size_t)(b * 4 + h) * 176 + rowbase + t];

  // ---- Phase A: T = H_rows @ M  (write bf16, XOR-swizzled) ----
  for (int jt = 0; jt < 2; ++jt){
    const int j0 = (w * 2 + jt) * 16;
    bf16x8 B[4];
    #pragma unroll
    for (int kk = 0; kk < 4; ++kk)
      B[kk] = *(const bf16x8*)(MTh + (j0 + l15) * 128 + kk * 32 + quad * 8);
    for (int nt = 0; nt < NT; ++nt){
      f32x4 acc = {0.f, 0.f, 0.f, 0.f};
      __builtin_amdgcn_s_setprio(1);
      #pragma unroll
      for (int kk = 0; kk < 4; ++kk){
        bf16x8 A = *(const bf16x8*)(Hb + (size_t)(rowbase + nt * 16 + l15) * 128 + kk * 32 + quad * 8);
        acc = __builtin_amdgcn_mfma_f32_16x16x32_bf16(A, B[kk], acc, 0, 0, 0);
      }
      __builtin_amdgcn_s_setprio(0);
      const int jcol = j0 + l15, ch = jcol >> 3;
      #pragma unroll
      for (int r = 0; r < 4; ++r){
        int row = nt * 16 + quad * 4 + r;
        Tsh[row * 128 + ((ch ^ (row & 15)) << 3) + (jcol & 7)] = (short)f2bf(acc[r]);
      }
    }
  }
  __syncthreads();

  // ---- Phase B: S = T @ H^T (+rank-1 terms), bf16 into Ssh ----
  for (int mi = 0; mi < 3; ++mi){
    const int mt = w + mi * 4;
    if (mt >= 11) break;
    const int m0 = mt * 16;
    bf16x8 B[4];
    #pragma unroll
    for (int kk = 0; kk < 4; ++kk)
      B[kk] = *(const bf16x8*)(Hb + (size_t)(m0 + l15) * 128 + kk * 32 + quad * 8);
    const int m = m0 + l15;
    const float u2v = u2s[m];
    for (int nt = 0; nt < NT; ++nt){
      f32x4 acc = {0.f, 0.f, 0.f, 0.f};
      __builtin_amdgcn_s_setprio(1);
      #pragma unroll
      for (int kk = 0; kk < 4; ++kk){
        int row = nt * 16 + l15;
        bf16x8 A = *(const bf16x8*)(&Tsh[row * 128 + (((kk * 4 + quad) ^ l15) << 3)]);
        acc = __builtin_amdgcn_mfma_f32_16x16x32_bf16(A, B[kk], acc, 0, 0, 0);
      }
      __builtin_amdgcn_s_setprio(0);
      #pragma unroll
      for (int r = 0; r < 4; ++r){
        int nl = nt * 16 + quad * 4 + r;
        float s = (acc[r] + u1s[nl] + u2v + c3v) * inv;
        Ssh[nl * 184 + m] = (short)f2bf(s);
      }
    }
  }
  __syncthreads();

  // ---- softmax: one row per wave pass; cols 0..167 valid, 168..175 -> 0 ----
  {
    const int nrw = NT * 4;                 // rows per wave
    for (int rr = 0; rr < nrw; ++rr){
      const int r = w * nrw + rr;
      short* rowp = &Ssh[r * 184];
      float v0 = bf2f((unsigned short)rowp[l]);
      float v1 = bf2f((unsigned short)rowp[64 + l]);
      float v2 = (l < 40) ? bf2f((unsigned short)rowp[128 + l]) : -1e30f;
      float mv = wmax(fmaxf(fmaxf(v0, v1), v2));
      float e0 = __expf(v0 - mv);
      float e1 = __expf(v1 - mv);
      float e2 = (l < 40) ? __expf(v2 - mv) : 0.f;
      float sinv = 1.f / wsum(e0 + e1 + e2);
      rowp[l]      = (short)f2bf(e0 * sinv);
      rowp[64 + l] = (short)f2bf(e1 * sinv);
      if (l < 56) rowp[128 + l] = (l < 40) ? (short)f2bf(e2 * sinv) : (short)0;
    }
  }
  __syncthreads();

  // ---- Phase G: GT = R @ H^T; fused dot with P -> scalar ----
  float tp = 0.f;
  for (int mi = 0; mi < 3; ++mi){
    const int mt = w + mi * 4;
    if (mt >= 11) break;
    const int m0 = mt * 16;
    bf16x8 B[4];
    #pragma unroll
    for (int kk = 0; kk < 4; ++kk)
      B[kk] = *(const bf16x8*)(Hb + (size_t)(m0 + l15) * 128 + kk * 32 + quad * 8);
    for (int nt = 0; nt < NT; ++nt){
      f32x4 acc = {0.f, 0.f, 0.f, 0.f};
      __builtin_amdgcn_s_setprio(1);
      #pragma unroll
      for (int kk = 0; kk < 4; ++kk){
        bf16x8 A = *(const bf16x8*)(Rh + (rowbase + nt * 16 + l15) * 128 + kk * 32 + quad * 8);
        acc = __builtin_amdgcn_mfma_f32_16x16x32_bf16(A, B[kk], acc, 0, 0, 0);
      }
      __builtin_amdgcn_s_setprio(0);
      #pragma unroll
      for (int r = 0; r < 4; ++r){
        int nl = nt * 16 + quad * 4 + r;
        if (rowbase + nl < N){
          float pv = bf2f((unsigned short)Ssh[nl * 184 + m0 + l15]);
          tp = fmaf(pv, acc[r], tp);
        }
      }
    }
  }
  float tot = rsum256(tp, red4);
  if (t == 0) atomicAdd(out + b, tot);
}

} // anonymous namespace

extern "C" void kernel_launch(void* const* d_in, const int* in_sizes, int n_in,
                              void* d_out, int out_size, void* d_ws, size_t ws_size,
                              hipStream_t stream) {
  (void)in_sizes; (void)n_in; (void)out_size;
  const float* X      = (const float*)d_in[0];
  const float* spa_w1 = (const float*)d_in[1];
  const float* spa_b1 = (const float*)d_in[2];
  const float* spa_w2 = (const float*)d_in[3];
  const float* spa_b2 = (const float*)d_in[4];
  const float* tem_w1 = (const float*)d_in[5];
  const float* tem_b1 = (const float*)d_in[6];
  const float* tem_w2 = (const float*)d_in[7];
  const float* tem_b2 = (const float*)d_in[8];
  const float* sgnn_w = (const float*)d_in[9];
  const float* sgnn_b = (const float*)d_in[10];
  const float* tgnn_w = (const float*)d_in[11];
  const float* tgnn_b = (const float*)d_in[12];
  const float* q_w    = (const float*)d_in[13];
  const float* q_b    = (const float*)d_in[14];
  const float* k_w    = (const float*)d_in[15];
  const float* k_b    = (const float*)d_in[16];
  const float* v_w    = (const float*)d_in[17];
  const float* v_b    = (const float*)d_in[18];
  const float* fc_w   = (const float*)d_in[19];
  const float* fc_b   = (const float*)d_in[20];
  float* out = (float*)d_out;

  if (ws_size < (size_t)182714368) return;

  char* wsb = (char*)d_ws;
  float* H   = (float*)wsb;                      // fp32 H [0, 88MB)
  float* u1g = (float*)(wsb + 50331648);         // overlays dead-H region (H dead after cast)
  float* u2g = (float*)(wsb + 53215232);
  char*  Rb  = wsb + 88080384;
  float* Xf  = (float*)Rb;
  float* As  = (float*)(Rb + 20971520);
  float* At  = (float*)(Rb + 27525120);
  short* Hbf = (short*)Rb;                       // overlays dead Xf/As/At after ht
  char*  Pb  = Rb + 46137344;
  short* MT  = (short*)Pb;                       // 131072 B
  short* Rbf = (short*)(Pb + 131072);            // 180224 B (4 heads x 176 x 128 bf16)
  float* c1  = (float*)(Pb + 311296);
  float* c2  = (float*)(Pb + 313344);
  float* c3  = (float*)(Pb + 315392);
  float* c4  = (float*)(Pb + 315408);

  feat_kernel<<<BSZ * P / 4, 256, 0, stream>>>(X, Xf);
  cumnorm_kernel<<<BSZ, 256, 0, stream>>>(Xf);
  adjt_kernel<<<BSZ, 256, 0, stream>>>(Xf, tem_w1, tem_b1, tem_w2, tem_b2, At);
  adjs_kernel<<<BSZ, 256, 0, stream>>>(Xf, spa_w1, spa_b1, spa_w2, spa_b2, As);
  hs_kernel<<<BSZ, 256, 0, stream>>>(Xf, As, sgnn_w, sgnn_b, H);
  ht_kernel<<<BSZ, 256, 0, stream>>>(Xf, At, tgnn_w, tgnn_b, H);
  prep_kernel<<<dim3(NH, 11), 256, 0, stream>>>(q_w, q_b, k_w, k_b, v_w, v_b, fc_w,
                                                MT, Rbf, c1, c2, c3, c4);
  cast_kernel<<<BSZ, 256, 0, stream>>>(H, Hbf);          // H fp32 dead after this
  uprep_kernel<<<BSZ, 256, 0, stream>>>(Hbf, c1, c2, u1g, u2g);
  initout_kernel<<<4, 256, 0, stream>>>(out, fc_b, c4);
  attn_mega<<<dim3(BSZ, NH, 4), 256, 0, stream>>>(Hbf, MT, Rbf, u1g, u2g, c3, out);
}

// Round 5
// 1511.200 us; speedup vs baseline: 1.0415x; 1.0131x over previous
//
#include <hip/hip_runtime.h>
#include <math.h>

namespace {

constexpr int BSZ  = 1024;
constexpr int P    = 128;
constexpr int HG   = 128;
constexpr int NH   = 4;
constexpr int N    = 168;     // P + IND
constexpr int NPAD = 176;     // padded token count (11 tiles of 16)

typedef short bf16x8 __attribute__((ext_vector_type(8)));
typedef float f32x4  __attribute__((ext_vector_type(4)));

__device__ __forceinline__ unsigned short f2bf(float x){
  union { float f; unsigned u; } v; v.f = x;
  unsigned r = (v.u + 0x7FFF + ((v.u >> 16) & 1)) >> 16;
  return (unsigned short)r;
}
__device__ __forceinline__ float bf2f(unsigned short b){
  union { unsigned u; float f; } v; v.u = ((unsigned)b) << 16;
  return v.f;
}

// ---------- wave (64-lane) butterfly reductions: result in ALL lanes ----------
__device__ __forceinline__ float wsum(float v){
  #pragma unroll
  for (int o = 1; o < 64; o <<= 1) v += __shfl_xor(v, o, 64);
  return v;
}
__device__ __forceinline__ float wmax(float v){
  #pragma unroll
  for (int o = 1; o < 64; o <<= 1) v = fmaxf(v, __shfl_xor(v, o, 64));
  return v;
}
__device__ __forceinline__ float wmin(float v){
  #pragma unroll
  for (int o = 1; o < 64; o <<= 1) v = fminf(v, __shfl_xor(v, o, 64));
  return v;
}
__device__ __forceinline__ float rsum256(float v, volatile float* red4){
  #pragma unroll
  for (int o = 32; o > 0; o >>= 1) v += __shfl_down(v, o, 64);
  __syncthreads();
  if ((threadIdx.x & 63) == 0) red4[threadIdx.x >> 6] = v;
  __syncthreads();
  return red4[0] + red4[1] + red4[2] + red4[3];
}

// ---------- K1: per-patch features, one WAVE per patch, no LDS, no barriers ----------
__global__ __launch_bounds__(256) void feat_kernel(const float* __restrict__ X,
                                                   float* __restrict__ Xf){
  const int wave = threadIdx.x >> 6, l = threadIdx.x & 63;
  const int pp = blockIdx.x * 4 + wave;          // patch id
  const float* xp = X + (size_t)pp * 128;
  const float x0 = xp[l];
  const float x1 = xp[l + 64];

  // ---- temporal ----
  float sum   = wsum(x0 + x1);
  float mean  = sum * (1.0f / 128.0f);
  float mx    = wmax(fmaxf(x0, x1));
  float mn    = wmin(fminf(x0, x1));
  float sumsq = wsum(fmaf(x0, x0, x1 * x1));
  float c0 = x0 - mean, c1_ = x1 - mean;
  float c0q = c0 * c0, c1q = c1_ * c1_;
  float m2 = wsum(c0q + c1q);
  float m3 = wsum(c0q * c0 + c1q * c1_);
  float m4 = wsum(c0q * c0q + c1q * c1q);
  float var = m2 * (1.0f / 127.0f);
  float sd  = sqrtf(var);
  float rms = sqrtf(sumsq * (1.0f / 128.0f));
  float ex0 = expf(x0 - mx), ex1 = expf(x1 - mx);
  float Z   = wsum(ex0 + ex1);
  float SxE = wsum(fmaf(ex0, x0, ex1 * x1));
  float ent = (mx + logf(Z)) - SxE / Z;
  const float lo = (float)(-1.0 + 1e-7), hi = (float)(1.0 - 1e-7);
  float a0 = asinf(fminf(fmaxf(x0, lo), hi));
  float a1 = asinf(fminf(fmaxf(x1, lo), hi));
  float amean = wsum(a0 + a1) * (1.0f / 128.0f);
  float ad0 = a0 - amean, ad1 = a1 - amean;
  float std_asin = sqrtf(wsum(fmaf(ad0, ad0, ad1 * ad1)) * (1.0f / 127.0f));
  float b0 = atanf(x0), b1v = atanf(x1);
  float bmean = wsum(b0 + b1v) * (1.0f / 128.0f);
  float bd0 = b0 - bmean, bd1 = b1v - bmean;
  float std_atan = sqrtf(wsum(fmaf(bd0, bd0, bd1 * bd1)) * (1.0f / 127.0f));
  float kurt = (m4 * (1.0f / 128.0f)) / (sd * sd * sd * sd) - 3.0f;
  float skew = (m3 * (1.0f / 128.0f)) / (sd * sd * sd);

  // ---- DFT: lane l computes bin l via rotation recurrence (64 folded steps) ----
  const float sign = (l & 1) ? -1.0f : 1.0f;
  float sC, cC;
  __sincosf((float)l * 0.049087385212340517f, &sC, &cC);   // 2*pi*l/128
  const float c1r = cC, s1r = -sC;
  const int x0i = __float_as_int(x0), x1i = __float_as_int(x1);
  float re = 0.f, im = 0.f;
  float wc = 1.f, ws = 0.f;
  #pragma unroll 8
  for (int tt = 0; tt < 32; ++tt){
    float s0v = __int_as_float(__builtin_amdgcn_readlane(x0i, tt));
    float s1v = __int_as_float(__builtin_amdgcn_readlane(x1i, tt));
    float se = fmaf(sign, s1v, s0v);
    re = fmaf(se, wc, re);
    im = fmaf(se, ws, im);
    float t1 = ws * s1r, t2 = ws * c1r;
    float nwc = fmaf(wc, c1r, -t1);
    ws = fmaf(wc, s1r, t2);
    wc = nwc;
  }
  { // exact reseed at tt=32: w = e^{-i*pi*l/2}
    int lm = l & 3;
    wc = (lm == 0) ? 1.f : (lm == 2) ? -1.f : 0.f;
    ws = (lm == 1) ? -1.f : (lm == 3) ? 1.f : 0.f;
  }
  #pragma unroll 8
  for (int tt = 32; tt < 64; ++tt){
    float s0v = __int_as_float(__builtin_amdgcn_readlane(x0i, tt));
    float s1v = __int_as_float(__builtin_amdgcn_readlane(x1i, tt));
    float se = fmaf(sign, s1v, s0v);
    re = fmaf(se, wc, re);
    im = fmaf(se, ws, im);
    float t1 = ws * s1r, t2 = ws * c1r;
    float nwc = fmaf(wc, c1r, -t1);
    ws = fmaf(wc, s1r, t2);
    wc = nwc;
  }
  float psd = fmaf(re, re, im * im) * 0.0078125f;          // bins 0..63 (lane l)
  float re64 = wsum(sign * (x0 + x1));                     // bin 64
  float psd64 = re64 * re64 * 0.0078125f;

  const float mult = (l == 0) ? 1.f : 2.f;
  float psum = wsum(psd * mult) + psd64;
  float p2   = wsum(psd * psd * mult) + psd64 * psd64;
  float vm   = wmax(psd);
  float maxp = fmaxf(vm, psd64);
  float meanfreq = (-0.5f * psd64) / psum;
  float pbw = sqrtf(p2 / psum);
  float cand = (psd == vm) ? (float)l : 1e9f;              // first-index argmax
  float lminf = wmin(cand);
  float fmaxv = (psd64 > vm) ? -0.5f : lminf * (1.0f / 128.0f);
  float maxamp = sqrtf(maxp * 128.0f);

  // ---- median (stable rank 64 of 128, multiplicity-aware ballot rank) ----
  float med = -0.5f;
  for (int kt = 0; kt < 64; ++kt){
    float vt = __int_as_float(__builtin_amdgcn_readlane(__float_as_int(psd), kt));
    unsigned long long mask = __ballot(psd < vt);
    int less = 2 * __popcll(mask) - (int)(mask & 1ull) + ((psd64 < vt) ? 1 : 0);
    if (less == 64) med = (float)kt * (1.0f / 128.0f);
    else if (less == 63 && kt >= 1) med = -(float)kt * (1.0f / 128.0f);
  }
  {
    unsigned long long mask = __ballot(psd < psd64);
    int less = 2 * __popcll(mask) - (int)(mask & 1ull);
    if (less == 64) med = -0.5f;
  }

  if (l == 0){
    float* o = Xf + (size_t)pp * 40;
    o[0]  = mx;  o[1]  = mn;  o[2]  = sd;   o[3]  = rms; o[4]  = mean;
    o[5]  = mx - mn;  o[6] = var;  o[7] = ent; o[8] = std_asin; o[9] = std_atan;
    o[10] = kurt; o[11] = skew;
    o[12] = meanfreq;
    o[13] = med;
    o[14] = psum;
    o[15] = 1.0f;
    o[16] = pbw;
    o[17] = maxp;
    o[18] = maxamp;
    o[19] = fmaxv;
  }
}

// ---------- K2: cumsum feature + per-sample normalization ----------
__global__ __launch_bounds__(256) void cumnorm_kernel(float* __restrict__ Xf){
  const int b = blockIdx.x, t = threadIdx.x;
  __shared__ float arr[128 * 40];
  __shared__ float red4[4];
  float* base = Xf + b * 5120;
  for (int idx = t; idx < 128 * 20; idx += 256){
    int p = idx / 20, c = idx - p * 20;
    arr[p * 40 + c] = base[p * 40 + c];
  }
  __syncthreads();
  if (t < 20){
    float acc = 0.f;
    for (int p = 0; p < 128; ++p){
      acc += arr[p * 40 + t];
      arr[p * 40 + 20 + t] = acc / sqrtf(fmaxf(fabsf(acc), 1e-12f));
    }
  }
  __syncthreads();
  float pa = 0.f;
  for (int idx = t; idx < 5120; idx += 256){ float v = arr[idx]; pa = fmaf(v, v, pa); }
  float nrm = sqrtf(rsum256(pa, red4));
  for (int idx = t; idx < 5120; idx += 256) base[idx] = arr[idx] / nrm;
}

// ---------- K3: A_t (register-tiled fp32; K-order per output unchanged) ----------
__global__ __launch_bounds__(256) void adjt_kernel(const float* __restrict__ Xf,
    const float* __restrict__ w1, const float* __restrict__ b1,
    const float* __restrict__ w2, const float* __restrict__ b2,
    float* __restrict__ At){
  const int b = blockIdx.x, t = threadIdx.x;
  __shared__ float xf[5120];          // stride 40
  __shared__ float T[128 * 64];
  const float* src = Xf + b * 5120;
  for (int idx = t; idx < 1280; idx += 256)
    *((float4*)xf + idx) = *((const float4*)src + idx);
  __syncthreads();

  // T1[i][k] = tanh(b1[k] + sum_c xf[i][c]*w1[c][k]); tile 8i x 4k per thread
  {
    const int k0 = (t & 15) * 4, i0 = (t >> 4) * 8;
    float4 bv = *(const float4*)&b1[k0];
    float acc[8][4];
    #pragma unroll
    for (int di = 0; di < 8; ++di){ acc[di][0]=bv.x; acc[di][1]=bv.y; acc[di][2]=bv.z; acc[di][3]=bv.w; }
    for (int c = 0; c < 40; ++c){
      float4 wv = *(const float4*)&w1[c * 64 + k0];
      #pragma unroll
      for (int di = 0; di < 8; ++di){
        float xv = xf[(i0 + di) * 40 + c];
        acc[di][0] = fmaf(xv, wv.x, acc[di][0]);
        acc[di][1] = fmaf(xv, wv.y, acc[di][1]);
        acc[di][2] = fmaf(xv, wv.z, acc[di][2]);
        acc[di][3] = fmaf(xv, wv.w, acc[di][3]);
      }
    }
    #pragma unroll
    for (int di = 0; di < 8; ++di){
      float4 o;
      o.x = tanhf(acc[di][0]); o.y = tanhf(acc[di][1]);
      o.z = tanhf(acc[di][2]); o.w = tanhf(acc[di][3]);
      *(float4*)&T[(i0 + di) * 64 + k0] = o;
    }
  }
  __syncthreads();

  // A_t[i][j] = b2[j] + sum_k T[i][k]*w2[k][j]; tile 16i x 4j per thread
  {
    const int j0 = (t & 31) * 4, i0 = (t >> 5) * 16;
    float4 bv = *(const float4*)&b2[j0];
    float acc[16][4];
    #pragma unroll
    for (int di = 0; di < 16; ++di){ acc[di][0]=bv.x; acc[di][1]=bv.y; acc[di][2]=bv.z; acc[di][3]=bv.w; }
    for (int k = 0; k < 64; ++k){
      float4 wv = *(const float4*)&w2[k * 128 + j0];
      #pragma unroll
      for (int di = 0; di < 16; ++di){
        float tv = T[(i0 + di) * 64 + k];
        acc[di][0] = fmaf(tv, wv.x, acc[di][0]);
        acc[di][1] = fmaf(tv, wv.y, acc[di][1]);
        acc[di][2] = fmaf(tv, wv.z, acc[di][2]);
        acc[di][3] = fmaf(tv, wv.w, acc[di][3]);
      }
    }
    float* dst = At + (size_t)b * 16384;
    #pragma unroll
    for (int di = 0; di < 16; ++di)
      *(float4*)&dst[(i0 + di) * 128 + j0] = *(float4*)acc[di];
  }
}

// ---------- K4: A_s ----------
__global__ __launch_bounds__(256) void adjs_kernel(const float* __restrict__ Xf,
    const float* __restrict__ w1, const float* __restrict__ b1,
    const float* __restrict__ w2, const float* __restrict__ b2,
    float* __restrict__ As){
  const int b = blockIdx.x, t = threadIdx.x;
  __shared__ float xf[5120];
  __shared__ float T2[40 * 64];
  const float* src = Xf + b * 5120;
  for (int idx = t; idx < 1280; idx += 256)
    *((float4*)xf + idx) = *((const float4*)src + idx);
  __syncthreads();
  for (int idx = t; idx < 40 * 64; idx += 256){
    int i = idx >> 6, k = idx & 63;
    float acc = b1[k];
    for (int p = 0; p < 128; ++p) acc = fmaf(xf[p * 40 + i], w1[p * 64 + k], acc);
    T2[idx] = tanhf(acc);
  }
  __syncthreads();
  float* dst = As + b * 1600;
  for (int idx = t; idx < 1600; idx += 256){
    int i = idx / 40, j = idx - i * 40;
    float acc = b2[j];
    #pragma unroll 8
    for (int k = 0; k < 64; ++k) acc = fmaf(T2[i * 64 + k], w2[k * 40 + j], acc);
    dst[idx] = acc;
  }
}

// ---------- K5: H_s (register-tiled) ----------
__global__ __launch_bounds__(256) void hs_kernel(const float* __restrict__ Xf,
    const float* __restrict__ As_g, const float* __restrict__ w, const float* __restrict__ bias,
    float* __restrict__ H){
  const int b = blockIdx.x, t = threadIdx.x;
  __shared__ float xf[5120];          // stride 40
  __shared__ float As[1600];
  __shared__ float M[40 * 128];
  const float* src = Xf + b * 5120;
  for (int idx = t; idx < 1280; idx += 256)
    *((float4*)xf + idx) = *((const float4*)src + idx);
  for (int idx = t; idx < 400; idx += 256)
    *((float4*)As + idx) = *((const float4*)(As_g + b * 1600) + idx);
  __syncthreads();

  // M[i][p] = sum_m As[i][m] * xf[p][m]; tile 5i x 4p, m in float4 steps
  {
    const int p0 = (t & 31) * 4, i0 = (t >> 5) * 5;
    float acc[5][4];
    #pragma unroll
    for (int di = 0; di < 5; ++di)
      #pragma unroll
      for (int dp = 0; dp < 4; ++dp) acc[di][dp] = 0.f;
    for (int m = 0; m < 40; m += 4){
      float4 a4[5], x4[4];
      #pragma unroll
      for (int di = 0; di < 5; ++di) a4[di] = *(const float4*)&As[(i0 + di) * 40 + m];
      #pragma unroll
      for (int dp = 0; dp < 4; ++dp) x4[dp] = *(const float4*)&xf[(p0 + dp) * 40 + m];
      #pragma unroll
      for (int dm = 0; dm < 4; ++dm)
        #pragma unroll
        for (int di = 0; di < 5; ++di){
          float av = (&a4[di].x)[dm];
          #pragma unroll
          for (int dp = 0; dp < 4; ++dp)
            acc[di][dp] = fmaf(av, (&x4[dp].x)[dm], acc[di][dp]);
        }
    }
    #pragma unroll
    for (int di = 0; di < 5; ++di)
      *(float4*)&M[(i0 + di) * 128 + p0] = *(float4*)acc[di];
  }
  __syncthreads();

  // H_s[i][j] = leaky(bias[j] + sum_p M[i][p]*w[p][j]); tile 5i x 4j
  {
    const int j0 = (t & 31) * 4, i0 = (t >> 5) * 5;
    float4 bv = *(const float4*)&bias[j0];
    float acc[5][4];
    #pragma unroll
    for (int di = 0; di < 5; ++di){ acc[di][0]=bv.x; acc[di][1]=bv.y; acc[di][2]=bv.z; acc[di][3]=bv.w; }
    for (int p = 0; p < 128; ++p){
      float4 wv = *(const float4*)&w[p * 128 + j0];
      #pragma unroll
      for (int di = 0; di < 5; ++di){
        float mv = M[(i0 + di) * 128 + p];
        acc[di][0] = fmaf(mv, wv.x, acc[di][0]);
        acc[di][1] = fmaf(mv, wv.y, acc[di][1]);
        acc[di][2] = fmaf(mv, wv.z, acc[di][2]);
        acc[di][3] = fmaf(mv, wv.w, acc[di][3]);
      }
    }
    float* dst = H + (size_t)b * (N * HG);
    #pragma unroll
    for (int di = 0; di < 5; ++di){
      float4 o;
      o.x = (acc[di][0] >= 0.f) ? acc[di][0] : 0.01f * acc[di][0];
      o.y = (acc[di][1] >= 0.f) ? acc[di][1] : 0.01f * acc[di][1];
      o.z = (acc[di][2] >= 0.f) ? acc[di][2] : 0.01f * acc[di][2];
      o.w = (acc[di][3] >= 0.f) ? acc[di][3] : 0.01f * acc[di][3];
      *(float4*)&dst[(i0 + di) * 128 + j0] = o;
    }
  }
}

// ---------- K6: H_t (register-tiled) ----------
__global__ __launch_bounds__(256) void ht_kernel(const float* __restrict__ Xf,
    const float* __restrict__ At_g, const float* __restrict__ w, const float* __restrict__ bias,
    float* __restrict__ H){
  const int b = blockIdx.x, t = threadIdx.x;
  __shared__ float xf[5120];          // stride 40
  __shared__ float M2[128 * 40];
  const float* src = Xf + b * 5120;
  for (int idx = t; idx < 1280; idx += 256)
    *((float4*)xf + idx) = *((const float4*)src + idx);
  __syncthreads();

  // M2[i][c] = sum_m At[i][m] * xf[m][c]; tile 4i x 5c, m in float4 steps
  {
    const int c0 = (t & 7) * 5, i0 = (t >> 3) * 4;
    const float* At = At_g + (size_t)b * 16384;
    float acc[4][5];
    #pragma unroll
    for (int di = 0; di < 4; ++di)
      #pragma unroll
      for (int dc = 0; dc < 5; ++dc) acc[di][dc] = 0.f;
    for (int m = 0; m < 128; m += 4){
      float4 a4[4];
      #pragma unroll
      for (int di = 0; di < 4; ++di) a4[di] = *(const float4*)&At[(i0 + di) * 128 + m];
      #pragma unroll
      for (int dm = 0; dm < 4; ++dm){
        float xv[5];
        #pragma unroll
        for (int dc = 0; dc < 5; ++dc) xv[dc] = xf[(m + dm) * 40 + c0 + dc];
        #pragma unroll
        for (int di = 0; di < 4; ++di){
          float av = (&a4[di].x)[dm];
          #pragma unroll
          for (int dc = 0; dc < 5; ++dc)
            acc[di][dc] = fmaf(av, xv[dc], acc[di][dc]);
        }
      }
    }
    #pragma unroll
    for (int di = 0; di < 4; ++di)
      #pragma unroll
      for (int dc = 0; dc < 5; ++dc)
        M2[(i0 + di) * 40 + c0 + dc] = acc[di][dc];
  }
  __syncthreads();

  // H_t[i][j] = leaky(bias[j] + sum_c M2[i][c]*w[c][j]); tile 16i x 4j
  {
    const int j0 = (t & 31) * 4, i0 = (t >> 5) * 16;
    float4 bv = *(const float4*)&bias[j0];
    float acc[16][4];
    #pragma unroll
    for (int di = 0; di < 16; ++di){ acc[di][0]=bv.x; acc[di][1]=bv.y; acc[di][2]=bv.z; acc[di][3]=bv.w; }
    for (int c = 0; c < 40; ++c){
      float4 wv = *(const float4*)&w[c * 128 + j0];
      #pragma unroll
      for (int di = 0; di < 16; ++di){
        float mv = M2[(i0 + di) * 40 + c];
        acc[di][0] = fmaf(mv, wv.x, acc[di][0]);
        acc[di][1] = fmaf(mv, wv.y, acc[di][1]);
        acc[di][2] = fmaf(mv, wv.z, acc[di][2]);
        acc[di][3] = fmaf(mv, wv.w, acc[di][3]);
      }
    }
    float* dst = H + (size_t)b * (N * HG) + 40 * 128;
    #pragma unroll
    for (int di = 0; di < 16; ++di){
      float4 o;
      o.x = (acc[di][0] >= 0.f) ? acc[di][0] : 0.01f * acc[di][0];
      o.y = (acc[di][1] >= 0.f) ? acc[di][1] : 0.01f * acc[di][1];
      o.z = (acc[di][2] >= 0.f) ? acc[di][2] : 0.01f * acc[di][2];
      o.w = (acc[di][3] >= 0.f) ? acc[di][3] : 0.01f * acc[di][3];
      *(float4*)&dst[(i0 + di) * 128 + j0] = o;
    }
  }
}

// out[b] = fc_b + sum_h c4[h]  (c4 = vb-term collapsed: rows of P sum to 1)
__global__ void initout_kernel(float* __restrict__ out, const float* __restrict__ fcb,
                               const float* __restrict__ c4){
  int i = blockIdx.x * 256 + threadIdx.x;
  float base = fcb[0] + c4[0] + c4[1] + c4[2] + c4[3];
  if (i < BSZ) out[i] = base;
}

// ---------- prep: per-head M^T, R = fcw·Wv^T, c1/c2/c3/c4; grid (NH, 11) ----------
// R[h][n][d] = sum_e fcw[n*512+h*128+e] * vw[h][d][e]  (b-independent!)
// c4[h] = sum_{n<168} sum_e vb[h][e] * fcw[n*512+h*128+e]
__global__ __launch_bounds__(256) void prep_kernel(
    const float* __restrict__ qw, const float* __restrict__ qb,
    const float* __restrict__ kw, const float* __restrict__ kb,
    const float* __restrict__ vw, const float* __restrict__ vb,
    const float* __restrict__ fcw,
    short* __restrict__ MT, short* __restrict__ Rbf,
    float* __restrict__ c1, float* __restrict__ c2,
    float* __restrict__ c3, float* __restrict__ c4){
  const int h = blockIdx.x, sl = blockIdx.y, t = threadIdx.x;
  const float* Q = qw + h * 16384;
  const float* K = kw + h * 16384;
  const float* V = vw + h * 16384;
  if (sl < 8){
    for (int idx = t; idx < 2048; idx += 256){
      int j = sl * 16 + (idx >> 7), d = idx & 127;
      float acc = 0.f;
      for (int e = 0; e < 128; ++e) acc = fmaf(Q[d * 128 + e], K[j * 128 + e], acc);
      MT[h * 16384 + j * 128 + d] = (short)f2bf(acc);     // MT[j][d] = M[d][j]
    }
    if (t < 16){
      int r = sl * 16 + t;
      float a = 0.f, bsum = 0.f;
      for (int e = 0; e < 128; ++e){
        a    = fmaf(Q[r * 128 + e], kb[h * 128 + e], a);
        bsum = fmaf(K[r * 128 + e], qb[h * 128 + e], bsum);
      }
      c1[h * 128 + r] = a;
      c2[h * 128 + r] = bsum;
    }
  }
  // R rows n in [sl*16, sl*16+16); zero-pad n >= 168
  for (int idx = t; idx < 2048; idx += 256){
    int n = sl * 16 + (idx >> 7), d = idx & 127;
    float acc = 0.f;
    if (n < N){
      const float* fr = fcw + n * 512 + h * 128;
      const float* vr = V + d * 128;
      for (int e = 0; e < 128; ++e) acc = fmaf(fr[e], vr[e], acc);
    }
    Rbf[h * 22528 + n * 128 + d] = (short)f2bf(acc);
  }
  if (sl == 0){
    if (t == 0){
      float a = 0.f;
      for (int e = 0; e < 128; ++e) a = fmaf(qb[h * 128 + e], kb[h * 128 + e], a);
      c3[h] = a;
    }
    if (t >= 64 && t < 128){                  // wave 1: c4 reduction
      int l = t - 64;
      float part = 0.f;
      for (int i = l; i < N * 128; i += 64){
        int n = i >> 7, e = i & 127;
        part = fmaf(fcw[n * 512 + h * 128 + e], vb[h * 128 + e], part);
      }
      part = wsum(part);
      if (l == 0) c4[h] = part;
    }
  }
}

// ---------- cast H -> bf16 with zero-padded rows 168..175 ----------
__global__ __launch_bounds__(256) void cast_kernel(const float* __restrict__ H,
                                                   short* __restrict__ Hbf){
  const int b = blockIdx.x;
  for (int idx = threadIdx.x; idx < NPAD * 128; idx += 256){
    int n = idx >> 7, d = idx & 127;
    float v = (n < N) ? H[((size_t)b * N + n) * 128 + d] : 0.f;
    Hbf[(size_t)b * NPAD * 128 + idx] = (short)f2bf(v);
  }
}

// ---------- u1/u2 precompute: u1[n]=H[n]·c1, u2[n]=H[n]·c2 per (b,h) ----------
__global__ __launch_bounds__(256) void uprep_kernel(const short* __restrict__ Hbf,
    const float* __restrict__ c1, const float* __restrict__ c2,
    float* __restrict__ u1g, float* __restrict__ u2g){
  const int b = blockIdx.x, t = threadIdx.x;
  for (int idx = t; idx < 176 * 4; idx += 256){
    int n = idx >> 2, h = idx & 3;
    const bf16x8* rp = (const bf16x8*)(Hbf + (size_t)b * NPAD * 128 + (size_t)n * 128);
    const float* C1 = c1 + h * 128;
    const float* C2 = c2 + h * 128;
    float a1 = 0.f, a2 = 0.f;
    for (int kk = 0; kk < 16; ++kk){
      bf16x8 v = rp[kk];
      #pragma unroll
      for (int j = 0; j < 8; ++j){
        float hv = bf2f((unsigned short)v[j]);
        a1 = fmaf(hv, C1[kk * 8 + j], a1);
        a2 = fmaf(hv, C2[kk * 8 + j], a2);
      }
    }
    u1g[(size_t)(b * 4 + h) * 176 + n] = a1;
    u2g[(size_t)(b * 4 + h) * 176 + n] = a2;
  }
}

// ---------- attention mega-kernel: grid (b, h, z), z=0..3 row chunks of 48 ----------
// Fused Phase BG: S = T@H^T and G = R@H^T share the SAME Hb B-fragments, computed
// in one loop (B-frags loaded once; Rh loads hide under Tsh-read+MFMA stream).
// accG[3][3] f32x4 held in registers across softmax — fully unrolled, compile-time
// indices only (rule #20: runtime-indexed ext_vector arrays go to scratch).
// Post-softmax tail is pure LDS reads + fmaf (no global, no MFMA). 3 barriers.
__global__ __launch_bounds__(256) void attn_mega(
    const short* __restrict__ Hbf, const short* __restrict__ MT,
    const short* __restrict__ Rbf,
    const float* __restrict__ u1g, const float* __restrict__ u2g,
    const float* __restrict__ c3g, float* __restrict__ out){
  const int b = blockIdx.x, h = blockIdx.y, z = blockIdx.z;
  const int NT = (z < 3) ? 3 : 2;
  const int rows = NT * 16;
  const int rowbase = z * 48;
  const int t = threadIdx.x;
  const int w = t >> 6, l = t & 63, quad = l >> 4, l15 = l & 15;

  __shared__ __align__(16) short Tsh[48 * 128];       // T (XOR-swizzled)
  __shared__ __align__(16) short Ssh[48 * 184 + 16];  // S then P (bf16, stride 184)
  __shared__ float u1s[48];
  __shared__ float u2s[176];
  __shared__ float red4[4];

  const short* Hb  = Hbf + (size_t)b * NPAD * 128;
  const short* MTh = MT + h * 16384;
  const short* Rh  = Rbf + h * 22528;
  const float c3v = c3g[h];
  const float inv = 0.08838834764831845f;   // 1/sqrt(128)

  if (t < 176) u2s[t] = u2g[(size_t)(b * 4 + h) * 176 + t];
  if (t < rows) u1s[t] = u1g[(size_t)(b * 4 + h) * 176 + rowbase + t];

  // ---- Phase A: T = H_rows @ M  (write bf16, XOR-swizzled) ----
  for (int jt = 0; jt < 2; ++jt){
    const int j0 = (w * 2 + jt) * 16;
    bf16x8 B[4];
    #pragma unroll
    for (int kk = 0; kk < 4; ++kk)
      B[kk] = *(const bf16x8*)(MTh + (j0 + l15) * 128 + kk * 32 + quad * 8);
    for (int nt = 0; nt < NT; ++nt){
      f32x4 acc = {0.f, 0.f, 0.f, 0.f};
      __builtin_amdgcn_s_setprio(1);
      #pragma unroll
      for (int kk = 0; kk < 4; ++kk){
        bf16x8 A = *(const bf16x8*)(Hb + (size_t)(rowbase + nt * 16 + l15) * 128 + kk * 32 + quad * 8);
        acc = __builtin_amdgcn_mfma_f32_16x16x32_bf16(A, B[kk], acc, 0, 0, 0);
      }
      __builtin_amdgcn_s_setprio(0);
      const int jcol = j0 + l15, ch = jcol >> 3;
      #pragma unroll
      for (int r = 0; r < 4; ++r){
        int row = nt * 16 + quad * 4 + r;
        Tsh[row * 128 + ((ch ^ (row & 15)) << 3) + (jcol & 7)] = (short)f2bf(acc[r]);
      }
    }
  }
  __syncthreads();

  // ---- Fused Phase BG ----
  f32x4 accG[3][3];
  #pragma unroll
  for (int mi = 0; mi < 3; ++mi)
    #pragma unroll
    for (int nt = 0; nt < 3; ++nt)
      accG[mi][nt] = (f32x4){0.f, 0.f, 0.f, 0.f};

  #pragma unroll
  for (int mi = 0; mi < 3; ++mi){
    const int mt = w + mi * 4;
    if (mt < 11){                               // wave-uniform guard (no divergence)
      const int m0 = mt * 16;
      bf16x8 B[4];
      #pragma unroll
      for (int kk = 0; kk < 4; ++kk)
        B[kk] = *(const bf16x8*)(Hb + (size_t)(m0 + l15) * 128 + kk * 32 + quad * 8);
      const int m = m0 + l15;
      const float u2v = u2s[m];
      #pragma unroll
      for (int nt = 0; nt < 3; ++nt){
        if (nt < NT){                           // wave-uniform guard
          f32x4 acc = {0.f, 0.f, 0.f, 0.f};
          f32x4 g = accG[mi][nt];
          __builtin_amdgcn_s_setprio(1);
          #pragma unroll
          for (int kk = 0; kk < 4; ++kk){
            int row = nt * 16 + l15;
            bf16x8 A = *(const bf16x8*)(&Tsh[row * 128 + (((kk * 4 + quad) ^ l15) << 3)]);
            acc = __builtin_amdgcn_mfma_f32_16x16x32_bf16(A, B[kk], acc, 0, 0, 0);
            bf16x8 RA = *(const bf16x8*)(Rh + (rowbase + nt * 16 + l15) * 128 + kk * 32 + quad * 8);
            g = __builtin_amdgcn_mfma_f32_16x16x32_bf16(RA, B[kk], g, 0, 0, 0);
          }
          __builtin_amdgcn_s_setprio(0);
          accG[mi][nt] = g;
          #pragma unroll
          for (int r = 0; r < 4; ++r){
            int nl = nt * 16 + quad * 4 + r;
            float s = (acc[r] + u1s[nl] + u2v + c3v) * inv;
            Ssh[nl * 184 + m] = (short)f2bf(s);
          }
        }
      }
    }
  }
  __syncthreads();

  // ---- softmax: one row per wave pass; cols 0..167 valid, 168..175 -> 0 ----
  {
    const int nrw = NT * 4;                 // rows per wave
    for (int rr = 0; rr < nrw; ++rr){
      const int r = w * nrw + rr;
      short* rowp = &Ssh[r * 184];
      float v0 = bf2f((unsigned short)rowp[l]);
      float v1 = bf2f((unsigned short)rowp[64 + l]);
      float v2 = (l < 40) ? bf2f((unsigned short)rowp[128 + l]) : -1e30f;
      float mv = wmax(fmaxf(fmaxf(v0, v1), v2));
      float e0 = __expf(v0 - mv);
      float e1 = __expf(v1 - mv);
      float e2 = (l < 40) ? __expf(v2 - mv) : 0.f;
      float sinv = 1.f / wsum(e0 + e1 + e2);
      rowp[l]      = (short)f2bf(e0 * sinv);
      rowp[64 + l] = (short)f2bf(e1 * sinv);
      if (l < 56) rowp[128 + l] = (l < 40) ? (short)f2bf(e2 * sinv) : (short)0;
    }
  }
  __syncthreads();

  // ---- tail: tp += P ∘ accG  (LDS reads + fmaf only) ----
  float tp = 0.f;
  #pragma unroll
  for (int mi = 0; mi < 3; ++mi){
    const int mt = w + mi * 4;
    if (mt < 11){
      const int m0 = mt * 16;
      #pragma unroll
      for (int nt = 0; nt < 3; ++nt){
        if (nt < NT){
          #pragma unroll
          for (int r = 0; r < 4; ++r){
            int nl = nt * 16 + quad * 4 + r;
            if (rowbase + nl < N){
              float pv = bf2f((unsigned short)Ssh[nl * 184 + m0 + l15]);
              tp = fmaf(pv, accG[mi][nt][r], tp);
            }
          }
        }
      }
    }
  }
  float tot = rsum256(tp, red4);
  if (t == 0) atomicAdd(out + b, tot);
}

} // anonymous namespace

extern "C" void kernel_launch(void* const* d_in, const int* in_sizes, int n_in,
                              void* d_out, int out_size, void* d_ws, size_t ws_size,
                              hipStream_t stream) {
  (void)in_sizes; (void)n_in; (void)out_size;
  const float* X      = (const float*)d_in[0];
  const float* spa_w1 = (const float*)d_in[1];
  const float* spa_b1 = (const float*)d_in[2];
  const float* spa_w2 = (const float*)d_in[3];
  const float* spa_b2 = (const float*)d_in[4];
  const float* tem_w1 = (const float*)d_in[5];
  const float* tem_b1 = (const float*)d_in[6];
  const float* tem_w2 = (const float*)d_in[7];
  const float* tem_b2 = (const float*)d_in[8];
  const float* sgnn_w = (const float*)d_in[9];
  const float* sgnn_b = (const float*)d_in[10];
  const float* tgnn_w = (const float*)d_in[11];
  const float* tgnn_b = (const float*)d_in[12];
  const float* q_w    = (const float*)d_in[13];
  const float* q_b    = (const float*)d_in[14];
  const float* k_w    = (const float*)d_in[15];
  const float* k_b    = (const float*)d_in[16];
  const float* v_w    = (const float*)d_in[17];
  const float* v_b    = (const float*)d_in[18];
  const float* fc_w   = (const float*)d_in[19];
  const float* fc_b   = (const float*)d_in[20];
  float* out = (float*)d_out;

  if (ws_size < (size_t)182714368) return;

  char* wsb = (char*)d_ws;
  float* H   = (float*)wsb;                      // fp32 H [0, 88MB)
  float* u1g = (float*)(wsb + 50331648);         // overlays dead-H region (H dead after cast)
  float* u2g = (float*)(wsb + 53215232);
  char*  Rb  = wsb + 88080384;
  float* Xf  = (float*)Rb;
  float* As  = (float*)(Rb + 20971520);
  float* At  = (float*)(Rb + 27525120);
  short* Hbf = (short*)Rb;                       // overlays dead Xf/As/At after ht
  char*  Pb  = Rb + 46137344;
  short* MT  = (short*)Pb;                       // 131072 B
  short* Rbf = (short*)(Pb + 131072);            // 180224 B (4 heads x 176 x 128 bf16)
  float* c1  = (float*)(Pb + 311296);
  float* c2  = (float*)(Pb + 313344);
  float* c3  = (float*)(Pb + 315392);
  float* c4  = (float*)(Pb + 315408);

  feat_kernel<<<BSZ * P / 4, 256, 0, stream>>>(X, Xf);
  cumnorm_kernel<<<BSZ, 256, 0, stream>>>(Xf);
  adjt_kernel<<<BSZ, 256, 0, stream>>>(Xf, tem_w1, tem_b1, tem_w2, tem_b2, At);
  adjs_kernel<<<BSZ, 256, 0, stream>>>(Xf, spa_w1, spa_b1, spa_w2, spa_b2, As);
  hs_kernel<<<BSZ, 256, 0, stream>>>(Xf, As, sgnn_w, sgnn_b, H);
  ht_kernel<<<BSZ, 256, 0, stream>>>(Xf, At, tgnn_w, tgnn_b, H);
  prep_kernel<<<dim3(NH, 11), 256, 0, stream>>>(q_w, q_b, k_w, k_b, v_w, v_b, fc_w,
                                                MT, Rbf, c1, c2, c3, c4);
  cast_kernel<<<BSZ, 256, 0, stream>>>(H, Hbf);          // H fp32 dead after this
  uprep_kernel<<<BSZ, 256, 0, stream>>>(Hbf, c1, c2, u1g, u2g);
  initout_kernel<<<4, 256, 0, stream>>>(out, fc_b, c4);
  attn_mega<<<dim3(BSZ, NH, 4), 256, 0, stream>>>(Hbf, MT, Rbf, u1g, u2g, c3, out);
}

// Round 6
// 1327.711 us; speedup vs baseline: 1.1854x; 1.1382x over previous
//
#include <hip/hip_runtime.h>
#include <math.h>

namespace {

constexpr int BSZ  = 1024;
constexpr int P    = 128;
constexpr int HG   = 128;
constexpr int NH   = 4;
constexpr int N    = 168;     // P + IND
constexpr int NPAD = 176;     // padded token count (11 tiles of 16)

typedef short bf16x8 __attribute__((ext_vector_type(8)));
typedef float f32x4  __attribute__((ext_vector_type(4)));

__device__ __forceinline__ unsigned short f2bf(float x){
  union { float f; unsigned u; } v; v.f = x;
  unsigned r = (v.u + 0x7FFF + ((v.u >> 16) & 1)) >> 16;
  return (unsigned short)r;
}
__device__ __forceinline__ float bf2f(unsigned short b){
  union { unsigned u; float f; } v; v.u = ((unsigned)b) << 16;
  return v.f;
}

// ---------- wave (64-lane) butterfly reductions: result in ALL lanes ----------
__device__ __forceinline__ float wsum(float v){
  #pragma unroll
  for (int o = 1; o < 64; o <<= 1) v += __shfl_xor(v, o, 64);
  return v;
}
__device__ __forceinline__ float wmax(float v){
  #pragma unroll
  for (int o = 1; o < 64; o <<= 1) v = fmaxf(v, __shfl_xor(v, o, 64));
  return v;
}
__device__ __forceinline__ float wmin(float v){
  #pragma unroll
  for (int o = 1; o < 64; o <<= 1) v = fminf(v, __shfl_xor(v, o, 64));
  return v;
}
__device__ __forceinline__ float rsum256(float v, volatile float* red4){
  #pragma unroll
  for (int o = 32; o > 0; o >>= 1) v += __shfl_down(v, o, 64);
  __syncthreads();
  if ((threadIdx.x & 63) == 0) red4[threadIdx.x >> 6] = v;
  __syncthreads();
  return red4[0] + red4[1] + red4[2] + red4[3];
}

// ---------- K1: per-patch features, one WAVE per patch, no LDS, no barriers ----------
__global__ __launch_bounds__(256) void feat_kernel(const float* __restrict__ X,
                                                   float* __restrict__ Xf){
  const int wave = threadIdx.x >> 6, l = threadIdx.x & 63;
  const int pp = blockIdx.x * 4 + wave;          // patch id
  const float* xp = X + (size_t)pp * 128;
  const float x0 = xp[l];
  const float x1 = xp[l + 64];

  // ---- temporal ----
  float sum   = wsum(x0 + x1);
  float mean  = sum * (1.0f / 128.0f);
  float mx    = wmax(fmaxf(x0, x1));
  float mn    = wmin(fminf(x0, x1));
  float sumsq = wsum(fmaf(x0, x0, x1 * x1));
  float c0 = x0 - mean, c1_ = x1 - mean;
  float c0q = c0 * c0, c1q = c1_ * c1_;
  float m2 = wsum(c0q + c1q);
  float m3 = wsum(c0q * c0 + c1q * c1_);
  float m4 = wsum(c0q * c0q + c1q * c1q);
  float var = m2 * (1.0f / 127.0f);
  float sd  = sqrtf(var);
  float rms = sqrtf(sumsq * (1.0f / 128.0f));
  float ex0 = expf(x0 - mx), ex1 = expf(x1 - mx);
  float Z   = wsum(ex0 + ex1);
  float SxE = wsum(fmaf(ex0, x0, ex1 * x1));
  float ent = (mx + logf(Z)) - SxE / Z;
  const float lo = (float)(-1.0 + 1e-7), hi = (float)(1.0 - 1e-7);
  float a0 = asinf(fminf(fmaxf(x0, lo), hi));
  float a1 = asinf(fminf(fmaxf(x1, lo), hi));
  float amean = wsum(a0 + a1) * (1.0f / 128.0f);
  float ad0 = a0 - amean, ad1 = a1 - amean;
  float std_asin = sqrtf(wsum(fmaf(ad0, ad0, ad1 * ad1)) * (1.0f / 127.0f));
  float b0 = atanf(x0), b1v = atanf(x1);
  float bmean = wsum(b0 + b1v) * (1.0f / 128.0f);
  float bd0 = b0 - bmean, bd1 = b1v - bmean;
  float std_atan = sqrtf(wsum(fmaf(bd0, bd0, bd1 * bd1)) * (1.0f / 127.0f));
  float kurt = (m4 * (1.0f / 128.0f)) / (sd * sd * sd * sd) - 3.0f;
  float skew = (m3 * (1.0f / 128.0f)) / (sd * sd * sd);

  // ---- DFT: lane l computes bin l via rotation recurrence (64 folded steps) ----
  const float sign = (l & 1) ? -1.0f : 1.0f;
  float sC, cC;
  __sincosf((float)l * 0.049087385212340517f, &sC, &cC);   // 2*pi*l/128
  const float c1r = cC, s1r = -sC;
  const int x0i = __float_as_int(x0), x1i = __float_as_int(x1);
  float re = 0.f, im = 0.f;
  float wc = 1.f, ws = 0.f;
  #pragma unroll 8
  for (int tt = 0; tt < 32; ++tt){
    float s0v = __int_as_float(__builtin_amdgcn_readlane(x0i, tt));
    float s1v = __int_as_float(__builtin_amdgcn_readlane(x1i, tt));
    float se = fmaf(sign, s1v, s0v);
    re = fmaf(se, wc, re);
    im = fmaf(se, ws, im);
    float t1 = ws * s1r, t2 = ws * c1r;
    float nwc = fmaf(wc, c1r, -t1);
    ws = fmaf(wc, s1r, t2);
    wc = nwc;
  }
  { // exact reseed at tt=32: w = e^{-i*pi*l/2}
    int lm = l & 3;
    wc = (lm == 0) ? 1.f : (lm == 2) ? -1.f : 0.f;
    ws = (lm == 1) ? -1.f : (lm == 3) ? 1.f : 0.f;
  }
  #pragma unroll 8
  for (int tt = 32; tt < 64; ++tt){
    float s0v = __int_as_float(__builtin_amdgcn_readlane(x0i, tt));
    float s1v = __int_as_float(__builtin_amdgcn_readlane(x1i, tt));
    float se = fmaf(sign, s1v, s0v);
    re = fmaf(se, wc, re);
    im = fmaf(se, ws, im);
    float t1 = ws * s1r, t2 = ws * c1r;
    float nwc = fmaf(wc, c1r, -t1);
    ws = fmaf(wc, s1r, t2);
    wc = nwc;
  }
  float psd = fmaf(re, re, im * im) * 0.0078125f;          // bins 0..63 (lane l)
  float re64 = wsum(sign * (x0 + x1));                     // bin 64
  float psd64 = re64 * re64 * 0.0078125f;

  const float mult = (l == 0) ? 1.f : 2.f;
  float psum = wsum(psd * mult) + psd64;
  float p2   = wsum(psd * psd * mult) + psd64 * psd64;
  float vm   = wmax(psd);
  float maxp = fmaxf(vm, psd64);
  float meanfreq = (-0.5f * psd64) / psum;
  float pbw = sqrtf(p2 / psum);
  float cand = (psd == vm) ? (float)l : 1e9f;              // first-index argmax
  float lminf = wmin(cand);
  float fmaxv = (psd64 > vm) ? -0.5f : lminf * (1.0f / 128.0f);
  float maxamp = sqrtf(maxp * 128.0f);

  // ---- median (stable rank 64 of 128, multiplicity-aware ballot rank) ----
  float med = -0.5f;
  for (int kt = 0; kt < 64; ++kt){
    float vt = __int_as_float(__builtin_amdgcn_readlane(__float_as_int(psd), kt));
    unsigned long long mask = __ballot(psd < vt);
    int less = 2 * __popcll(mask) - (int)(mask & 1ull) + ((psd64 < vt) ? 1 : 0);
    if (less == 64) med = (float)kt * (1.0f / 128.0f);
    else if (less == 63 && kt >= 1) med = -(float)kt * (1.0f / 128.0f);
  }
  {
    unsigned long long mask = __ballot(psd < psd64);
    int less = 2 * __popcll(mask) - (int)(mask & 1ull);
    if (less == 64) med = -0.5f;
  }

  if (l == 0){
    float* o = Xf + (size_t)pp * 40;
    o[0]  = mx;  o[1]  = mn;  o[2]  = sd;   o[3]  = rms; o[4]  = mean;
    o[5]  = mx - mn;  o[6] = var;  o[7] = ent; o[8] = std_asin; o[9] = std_atan;
    o[10] = kurt; o[11] = skew;
    o[12] = meanfreq;
    o[13] = med;
    o[14] = psum;
    o[15] = 1.0f;
    o[16] = pbw;
    o[17] = maxp;
    o[18] = maxamp;
    o[19] = fmaxv;
  }
}

// ---------- K2: cumsum feature + per-sample normalization ----------
__global__ __launch_bounds__(256) void cumnorm_kernel(float* __restrict__ Xf){
  const int b = blockIdx.x, t = threadIdx.x;
  __shared__ float arr[128 * 40];
  __shared__ float red4[4];
  float* base = Xf + b * 5120;
  for (int idx = t; idx < 128 * 20; idx += 256){
    int p = idx / 20, c = idx - p * 20;
    arr[p * 40 + c] = base[p * 40 + c];
  }
  __syncthreads();
  if (t < 20){
    float acc = 0.f;
    for (int p = 0; p < 128; ++p){
      acc += arr[p * 40 + t];
      arr[p * 40 + 20 + t] = acc / sqrtf(fmaxf(fabsf(acc), 1e-12f));
    }
  }
  __syncthreads();
  float pa = 0.f;
  for (int idx = t; idx < 5120; idx += 256){ float v = arr[idx]; pa = fmaf(v, v, pa); }
  float nrm = sqrtf(rsum256(pa, red4));
  for (int idx = t; idx < 5120; idx += 256) base[idx] = arr[idx] / nrm;
}

// ---------- K3: A_t (register-tiled fp32; K-order per output unchanged) ----------
__global__ __launch_bounds__(256) void adjt_kernel(const float* __restrict__ Xf,
    const float* __restrict__ w1, const float* __restrict__ b1,
    const float* __restrict__ w2, const float* __restrict__ b2,
    float* __restrict__ At){
  const int b = blockIdx.x, t = threadIdx.x;
  __shared__ float xf[5120];          // stride 40
  __shared__ float T[128 * 64];
  const float* src = Xf + b * 5120;
  for (int idx = t; idx < 1280; idx += 256)
    *((float4*)xf + idx) = *((const float4*)src + idx);
  __syncthreads();

  // T1[i][k] = tanh(b1[k] + sum_c xf[i][c]*w1[c][k]); tile 8i x 4k per thread
  {
    const int k0 = (t & 15) * 4, i0 = (t >> 4) * 8;
    float4 bv = *(const float4*)&b1[k0];
    float acc[8][4];
    #pragma unroll
    for (int di = 0; di < 8; ++di){ acc[di][0]=bv.x; acc[di][1]=bv.y; acc[di][2]=bv.z; acc[di][3]=bv.w; }
    for (int c = 0; c < 40; ++c){
      float4 wv = *(const float4*)&w1[c * 64 + k0];
      #pragma unroll
      for (int di = 0; di < 8; ++di){
        float xv = xf[(i0 + di) * 40 + c];
        acc[di][0] = fmaf(xv, wv.x, acc[di][0]);
        acc[di][1] = fmaf(xv, wv.y, acc[di][1]);
        acc[di][2] = fmaf(xv, wv.z, acc[di][2]);
        acc[di][3] = fmaf(xv, wv.w, acc[di][3]);
      }
    }
    #pragma unroll
    for (int di = 0; di < 8; ++di){
      float4 o;
      o.x = tanhf(acc[di][0]); o.y = tanhf(acc[di][1]);
      o.z = tanhf(acc[di][2]); o.w = tanhf(acc[di][3]);
      *(float4*)&T[(i0 + di) * 64 + k0] = o;
    }
  }
  __syncthreads();

  // A_t[i][j] = b2[j] + sum_k T[i][k]*w2[k][j]; tile 16i x 4j per thread
  {
    const int j0 = (t & 31) * 4, i0 = (t >> 5) * 16;
    float4 bv = *(const float4*)&b2[j0];
    float acc[16][4];
    #pragma unroll
    for (int di = 0; di < 16; ++di){ acc[di][0]=bv.x; acc[di][1]=bv.y; acc[di][2]=bv.z; acc[di][3]=bv.w; }
    for (int k = 0; k < 64; ++k){
      float4 wv = *(const float4*)&w2[k * 128 + j0];
      #pragma unroll
      for (int di = 0; di < 16; ++di){
        float tv = T[(i0 + di) * 64 + k];
        acc[di][0] = fmaf(tv, wv.x, acc[di][0]);
        acc[di][1] = fmaf(tv, wv.y, acc[di][1]);
        acc[di][2] = fmaf(tv, wv.z, acc[di][2]);
        acc[di][3] = fmaf(tv, wv.w, acc[di][3]);
      }
    }
    float* dst = At + (size_t)b * 16384;
    #pragma unroll
    for (int di = 0; di < 16; ++di)
      *(float4*)&dst[(i0 + di) * 128 + j0] = *(float4*)acc[di];
  }
}

// ---------- K4: A_s ----------
__global__ __launch_bounds__(256) void adjs_kernel(const float* __restrict__ Xf,
    const float* __restrict__ w1, const float* __restrict__ b1,
    const float* __restrict__ w2, const float* __restrict__ b2,
    float* __restrict__ As){
  const int b = blockIdx.x, t = threadIdx.x;
  __shared__ float xf[5120];
  __shared__ float T2[40 * 64];
  const float* src = Xf + b * 5120;
  for (int idx = t; idx < 1280; idx += 256)
    *((float4*)xf + idx) = *((const float4*)src + idx);
  __syncthreads();
  for (int idx = t; idx < 40 * 64; idx += 256){
    int i = idx >> 6, k = idx & 63;
    float acc = b1[k];
    for (int p = 0; p < 128; ++p) acc = fmaf(xf[p * 40 + i], w1[p * 64 + k], acc);
    T2[idx] = tanhf(acc);
  }
  __syncthreads();
  float* dst = As + b * 1600;
  for (int idx = t; idx < 1600; idx += 256){
    int i = idx / 40, j = idx - i * 40;
    float acc = b2[j];
    #pragma unroll 8
    for (int k = 0; k < 64; ++k) acc = fmaf(T2[i * 64 + k], w2[k * 40 + j], acc);
    dst[idx] = acc;
  }
}

// ---------- K5: H_s (register-tiled) ----------
__global__ __launch_bounds__(256) void hs_kernel(const float* __restrict__ Xf,
    const float* __restrict__ As_g, const float* __restrict__ w, const float* __restrict__ bias,
    float* __restrict__ H){
  const int b = blockIdx.x, t = threadIdx.x;
  __shared__ float xf[5120];          // stride 40
  __shared__ float As[1600];
  __shared__ float M[40 * 128];
  const float* src = Xf + b * 5120;
  for (int idx = t; idx < 1280; idx += 256)
    *((float4*)xf + idx) = *((const float4*)src + idx);
  for (int idx = t; idx < 400; idx += 256)
    *((float4*)As + idx) = *((const float4*)(As_g + b * 1600) + idx);
  __syncthreads();

  // M[i][p] = sum_m As[i][m] * xf[p][m]; tile 5i x 4p, m in float4 steps
  {
    const int p0 = (t & 31) * 4, i0 = (t >> 5) * 5;
    float acc[5][4];
    #pragma unroll
    for (int di = 0; di < 5; ++di)
      #pragma unroll
      for (int dp = 0; dp < 4; ++dp) acc[di][dp] = 0.f;
    for (int m = 0; m < 40; m += 4){
      float4 a4[5], x4[4];
      #pragma unroll
      for (int di = 0; di < 5; ++di) a4[di] = *(const float4*)&As[(i0 + di) * 40 + m];
      #pragma unroll
      for (int dp = 0; dp < 4; ++dp) x4[dp] = *(const float4*)&xf[(p0 + dp) * 40 + m];
      #pragma unroll
      for (int dm = 0; dm < 4; ++dm)
        #pragma unroll
        for (int di = 0; di < 5; ++di){
          float av = (&a4[di].x)[dm];
          #pragma unroll
          for (int dp = 0; dp < 4; ++dp)
            acc[di][dp] = fmaf(av, (&x4[dp].x)[dm], acc[di][dp]);
        }
    }
    #pragma unroll
    for (int di = 0; di < 5; ++di)
      *(float4*)&M[(i0 + di) * 128 + p0] = *(float4*)acc[di];
  }
  __syncthreads();

  // H_s[i][j] = leaky(bias[j] + sum_p M[i][p]*w[p][j]); tile 5i x 4j
  {
    const int j0 = (t & 31) * 4, i0 = (t >> 5) * 5;
    float4 bv = *(const float4*)&bias[j0];
    float acc[5][4];
    #pragma unroll
    for (int di = 0; di < 5; ++di){ acc[di][0]=bv.x; acc[di][1]=bv.y; acc[di][2]=bv.z; acc[di][3]=bv.w; }
    for (int p = 0; p < 128; ++p){
      float4 wv = *(const float4*)&w[p * 128 + j0];
      #pragma unroll
      for (int di = 0; di < 5; ++di){
        float mv = M[(i0 + di) * 128 + p];
        acc[di][0] = fmaf(mv, wv.x, acc[di][0]);
        acc[di][1] = fmaf(mv, wv.y, acc[di][1]);
        acc[di][2] = fmaf(mv, wv.z, acc[di][2]);
        acc[di][3] = fmaf(mv, wv.w, acc[di][3]);
      }
    }
    float* dst = H + (size_t)b * (N * HG);
    #pragma unroll
    for (int di = 0; di < 5; ++di){
      float4 o;
      o.x = (acc[di][0] >= 0.f) ? acc[di][0] : 0.01f * acc[di][0];
      o.y = (acc[di][1] >= 0.f) ? acc[di][1] : 0.01f * acc[di][1];
      o.z = (acc[di][2] >= 0.f) ? acc[di][2] : 0.01f * acc[di][2];
      o.w = (acc[di][3] >= 0.f) ? acc[di][3] : 0.01f * acc[di][3];
      *(float4*)&dst[(i0 + di) * 128 + j0] = o;
    }
  }
}

// ---------- K6: H_t (register-tiled) ----------
__global__ __launch_bounds__(256) void ht_kernel(const float* __restrict__ Xf,
    const float* __restrict__ At_g, const float* __restrict__ w, const float* __restrict__ bias,
    float* __restrict__ H){
  const int b = blockIdx.x, t = threadIdx.x;
  __shared__ float xf[5120];          // stride 40
  __shared__ float M2[128 * 40];
  const float* src = Xf + b * 5120;
  for (int idx = t; idx < 1280; idx += 256)
    *((float4*)xf + idx) = *((const float4*)src + idx);
  __syncthreads();

  // M2[i][c] = sum_m At[i][m] * xf[m][c]; tile 4i x 5c, m in float4 steps
  {
    const int c0 = (t & 7) * 5, i0 = (t >> 3) * 4;
    const float* At = At_g + (size_t)b * 16384;
    float acc[4][5];
    #pragma unroll
    for (int di = 0; di < 4; ++di)
      #pragma unroll
      for (int dc = 0; dc < 5; ++dc) acc[di][dc] = 0.f;
    for (int m = 0; m < 128; m += 4){
      float4 a4[4];
      #pragma unroll
      for (int di = 0; di < 4; ++di) a4[di] = *(const float4*)&At[(i0 + di) * 128 + m];
      #pragma unroll
      for (int dm = 0; dm < 4; ++dm){
        float xv[5];
        #pragma unroll
        for (int dc = 0; dc < 5; ++dc) xv[dc] = xf[(m + dm) * 40 + c0 + dc];
        #pragma unroll
        for (int di = 0; di < 4; ++di){
          float av = (&a4[di].x)[dm];
          #pragma unroll
          for (int dc = 0; dc < 5; ++dc)
            acc[di][dc] = fmaf(av, xv[dc], acc[di][dc]);
        }
      }
    }
    #pragma unroll
    for (int di = 0; di < 4; ++di)
      #pragma unroll
      for (int dc = 0; dc < 5; ++dc)
        M2[(i0 + di) * 40 + c0 + dc] = acc[di][dc];
  }
  __syncthreads();

  // H_t[i][j] = leaky(bias[j] + sum_c M2[i][c]*w[c][j]); tile 16i x 4j
  {
    const int j0 = (t & 31) * 4, i0 = (t >> 5) * 16;
    float4 bv = *(const float4*)&bias[j0];
    float acc[16][4];
    #pragma unroll
    for (int di = 0; di < 16; ++di){ acc[di][0]=bv.x; acc[di][1]=bv.y; acc[di][2]=bv.z; acc[di][3]=bv.w; }
    for (int c = 0; c < 40; ++c){
      float4 wv = *(const float4*)&w[c * 128 + j0];
      #pragma unroll
      for (int di = 0; di < 16; ++di){
        float mv = M2[(i0 + di) * 40 + c];
        acc[di][0] = fmaf(mv, wv.x, acc[di][0]);
        acc[di][1] = fmaf(mv, wv.y, acc[di][1]);
        acc[di][2] = fmaf(mv, wv.z, acc[di][2]);
        acc[di][3] = fmaf(mv, wv.w, acc[di][3]);
      }
    }
    float* dst = H + (size_t)b * (N * HG) + 40 * 128;
    #pragma unroll
    for (int di = 0; di < 16; ++di){
      float4 o;
      o.x = (acc[di][0] >= 0.f) ? acc[di][0] : 0.01f * acc[di][0];
      o.y = (acc[di][1] >= 0.f) ? acc[di][1] : 0.01f * acc[di][1];
      o.z = (acc[di][2] >= 0.f) ? acc[di][2] : 0.01f * acc[di][2];
      o.w = (acc[di][3] >= 0.f) ? acc[di][3] : 0.01f * acc[di][3];
      *(float4*)&dst[(i0 + di) * 128 + j0] = o;
    }
  }
}

// out[b] = fc_b + sum_h c4[h]  (c4 = vb-term collapsed: rows of P sum to 1)
__global__ void initout_kernel(float* __restrict__ out, const float* __restrict__ fcb,
                               const float* __restrict__ c4){
  int i = blockIdx.x * 256 + threadIdx.x;
  float base = fcb[0] + c4[0] + c4[1] + c4[2] + c4[3];
  if (i < BSZ) out[i] = base;
}

// ---------- prep: per-head M^T, R = fcw·Wv^T, c1/c2/c3/c4; grid (NH, 11) ----------
// R[h][n][d] = sum_e fcw[n*512+h*128+e] * vw[h][d][e]  (b-independent!)
// c4[h] = sum_{n<168} sum_e vb[h][e] * fcw[n*512+h*128+e]
__global__ __launch_bounds__(256) void prep_kernel(
    const float* __restrict__ qw, const float* __restrict__ qb,
    const float* __restrict__ kw, const float* __restrict__ kb,
    const float* __restrict__ vw, const float* __restrict__ vb,
    const float* __restrict__ fcw,
    short* __restrict__ MT, short* __restrict__ Rbf,
    float* __restrict__ c1, float* __restrict__ c2,
    float* __restrict__ c3, float* __restrict__ c4){
  const int h = blockIdx.x, sl = blockIdx.y, t = threadIdx.x;
  const float* Q = qw + h * 16384;
  const float* K = kw + h * 16384;
  const float* V = vw + h * 16384;
  if (sl < 8){
    for (int idx = t; idx < 2048; idx += 256){
      int j = sl * 16 + (idx >> 7), d = idx & 127;
      float acc = 0.f;
      for (int e = 0; e < 128; ++e) acc = fmaf(Q[d * 128 + e], K[j * 128 + e], acc);
      MT[h * 16384 + j * 128 + d] = (short)f2bf(acc);     // MT[j][d] = M[d][j]
    }
    if (t < 16){
      int r = sl * 16 + t;
      float a = 0.f, bsum = 0.f;
      for (int e = 0; e < 128; ++e){
        a    = fmaf(Q[r * 128 + e], kb[h * 128 + e], a);
        bsum = fmaf(K[r * 128 + e], qb[h * 128 + e], bsum);
      }
      c1[h * 128 + r] = a;
      c2[h * 128 + r] = bsum;
    }
  }
  // R rows n in [sl*16, sl*16+16); zero-pad n >= 168
  for (int idx = t; idx < 2048; idx += 256){
    int n = sl * 16 + (idx >> 7), d = idx & 127;
    float acc = 0.f;
    if (n < N){
      const float* fr = fcw + n * 512 + h * 128;
      const float* vr = V + d * 128;
      for (int e = 0; e < 128; ++e) acc = fmaf(fr[e], vr[e], acc);
    }
    Rbf[h * 22528 + n * 128 + d] = (short)f2bf(acc);
  }
  if (sl == 0){
    if (t == 0){
      float a = 0.f;
      for (int e = 0; e < 128; ++e) a = fmaf(qb[h * 128 + e], kb[h * 128 + e], a);
      c3[h] = a;
    }
    if (t >= 64 && t < 128){                  // wave 1: c4 reduction
      int l = t - 64;
      float part = 0.f;
      for (int i = l; i < N * 128; i += 64){
        int n = i >> 7, e = i & 127;
        part = fmaf(fcw[n * 512 + h * 128 + e], vb[h * 128 + e], part);
      }
      part = wsum(part);
      if (l == 0) c4[h] = part;
    }
  }
}

// ---------- cast H -> bf16 with zero-padded rows 168..175 ----------
__global__ __launch_bounds__(256) void cast_kernel(const float* __restrict__ H,
                                                   short* __restrict__ Hbf){
  const int b = blockIdx.x;
  for (int idx = threadIdx.x; idx < NPAD * 128; idx += 256){
    int n = idx >> 7, d = idx & 127;
    float v = (n < N) ? H[((size_t)b * N + n) * 128 + d] : 0.f;
    Hbf[(size_t)b * NPAD * 128 + idx] = (short)f2bf(v);
  }
}

// ---------- u1/u2 precompute: u1[n]=H[n]·c1, u2[n]=H[n]·c2 per (b,h) ----------
__global__ __launch_bounds__(256) void uprep_kernel(const short* __restrict__ Hbf,
    const float* __restrict__ c1, const float* __restrict__ c2,
    float* __restrict__ u1g, float* __restrict__ u2g){
  const int b = blockIdx.x, t = threadIdx.x;
  for (int idx = t; idx < 176 * 4; idx += 256){
    int n = idx >> 2, h = idx & 3;
    const bf16x8* rp = (const bf16x8*)(Hbf + (size_t)b * NPAD * 128 + (size_t)n * 128);
    const float* C1 = c1 + h * 128;
    const float* C2 = c2 + h * 128;
    float a1 = 0.f, a2 = 0.f;
    for (int kk = 0; kk < 16; ++kk){
      bf16x8 v = rp[kk];
      #pragma unroll
      for (int j = 0; j < 8; ++j){
        float hv = bf2f((unsigned short)v[j]);
        a1 = fmaf(hv, C1[kk * 8 + j], a1);
        a2 = fmaf(hv, C2[kk * 8 + j], a2);
      }
    }
    u1g[(size_t)(b * 4 + h) * 176 + n] = a1;
    u2g[(size_t)(b * 4 + h) * 176 + n] = a2;
  }
}

// ---------- attention, flash-style: grid (b, zt=0..10), wave w = head w ----------
// Each WAVE independently handles head h, rows [zt*16, zt*16+16): Phase A (T=H@M,
// private 4KB LDS slice), then 11 m-tiles of fused S/G MFMA with PER-LANE online
// softmax (running M/A/D; A accumulates e^{s-M}·G). NO __syncthreads in the hot
// path (in-wave DS ordering is HW-guaranteed). 16-lane butterfly merges (M,A,D);
// out contribution = sum_n A_n/D_n. All loops literal-bound + unrolled (rule #20).
__global__ __launch_bounds__(256, 4) void attn_flash(
    const short* __restrict__ Hbf, const short* __restrict__ MT,
    const short* __restrict__ Rbf,
    const float* __restrict__ u1g, const float* __restrict__ u2g,
    const float* __restrict__ c3g, float* __restrict__ out){
  const int b = blockIdx.x, zt = blockIdx.y;
  const int t = threadIdx.x;
  const int h = t >> 6, l = t & 63, quad = l >> 4, l15 = l & 15;
  const int rowbase = zt * 16;

  __shared__ __align__(16) short Tsh[4 * 16 * 128];   // 4KB per wave, private slices
  __shared__ float red4[4];

  const short* Hb  = Hbf + (size_t)b * NPAD * 128;
  const short* MTh = MT + h * 16384;
  const short* Rh  = Rbf + h * 22528;
  const float c3v = c3g[h];
  const float inv = 0.08838834764831845f;   // 1/sqrt(128)
  const float* u1p = u1g + (size_t)(b * 4 + h) * 176;
  const float* u2p = u2g + (size_t)(b * 4 + h) * 176;

  // A-frags (H chunk rows) and R-frags: loaded once, reused across all tiles
  bf16x8 HA[4], RA[4];
  #pragma unroll
  for (int kk = 0; kk < 4; ++kk){
    HA[kk] = *(const bf16x8*)(Hb + (size_t)(rowbase + l15) * 128 + kk * 32 + quad * 8);
    RA[kk] = *(const bf16x8*)(Rh + (rowbase + l15) * 128 + kk * 32 + quad * 8);
  }
  float u1v[4];
  #pragma unroll
  for (int r = 0; r < 4; ++r) u1v[r] = u1p[rowbase + quad * 4 + r];

  // ---- Phase A: T = H_chunk @ M -> private LDS slice (XOR-swizzled) ----
  short* Tw = Tsh + h * 2048;
  #pragma unroll
  for (int jt = 0; jt < 8; ++jt){
    const int j0 = jt * 16;
    f32x4 acc = {0.f, 0.f, 0.f, 0.f};
    #pragma unroll
    for (int kk = 0; kk < 4; ++kk){
      bf16x8 Bv = *(const bf16x8*)(MTh + (j0 + l15) * 128 + kk * 32 + quad * 8);
      acc = __builtin_amdgcn_mfma_f32_16x16x32_bf16(HA[kk], Bv, acc, 0, 0, 0);
    }
    const int jcol = j0 + l15, ch = jcol >> 3;
    #pragma unroll
    for (int r = 0; r < 4; ++r){
      int row = quad * 4 + r;
      Tw[row * 128 + ((ch ^ row) << 3) + (jcol & 7)] = (short)f2bf(acc[r]);
    }
  }
  // no barrier: same-wave DS ops are ordered; compiler inserts lgkmcnt waits

  // ---- Phase BG + per-lane online softmax over 11 m-tiles ----
  float Mx[4], Av[4], Dv[4];
  #pragma unroll
  for (int r = 0; r < 4; ++r){ Mx[r] = -1e30f; Av[r] = 0.f; Dv[r] = 0.f; }

  #pragma unroll
  for (int mt = 0; mt < 11; ++mt){
    const int m0 = mt * 16;
    bf16x8 Bv[4];
    #pragma unroll
    for (int kk = 0; kk < 4; ++kk)
      Bv[kk] = *(const bf16x8*)(Hb + (size_t)(m0 + l15) * 128 + kk * 32 + quad * 8);
    const float u2v = u2p[m0 + l15];
    f32x4 acc = {0.f, 0.f, 0.f, 0.f};
    f32x4 g   = {0.f, 0.f, 0.f, 0.f};
    #pragma unroll
    for (int kk = 0; kk < 4; ++kk){
      bf16x8 A = *(const bf16x8*)(Tw + l15 * 128 + (((kk * 4 + quad) ^ l15) << 3));
      acc = __builtin_amdgcn_mfma_f32_16x16x32_bf16(A, Bv[kk], acc, 0, 0, 0);
      g   = __builtin_amdgcn_mfma_f32_16x16x32_bf16(RA[kk], Bv[kk], g, 0, 0, 0);
    }
    const bool padcol = (mt == 10) && (l15 >= 8);     // cols 168..175 masked
    #pragma unroll
    for (int r = 0; r < 4; ++r){
      float s = padcol ? -1e30f : (acc[r] + u1v[r] + u2v + c3v) * inv;
      float Mn = fmaxf(Mx[r], s);
      float ea = __expf(Mx[r] - Mn);
      float eb = __expf(s - Mn);
      Av[r] = fmaf(Av[r], ea, eb * g[r]);
      Dv[r] = fmaf(Dv[r], ea, eb);
      Mx[r] = Mn;
    }
  }

  // ---- merge (M,A,D) across the 16 l15 lanes (stays within quad) ----
  #pragma unroll
  for (int r = 0; r < 4; ++r){
    #pragma unroll
    for (int o = 1; o < 16; o <<= 1){
      float M2 = __shfl_xor(Mx[r], o, 64);
      float A2 = __shfl_xor(Av[r], o, 64);
      float D2 = __shfl_xor(Dv[r], o, 64);
      float Mn = fmaxf(Mx[r], M2);
      float ea = __expf(Mx[r] - Mn);
      float eb = __expf(M2 - Mn);
      Av[r] = fmaf(Av[r], ea, A2 * eb);
      Dv[r] = fmaf(Dv[r], ea, D2 * eb);
      Mx[r] = Mn;
    }
  }

  // ---- per-row A/D, replicated over 16 lanes -> scale by 1/16 ----
  float tp = 0.f;
  #pragma unroll
  for (int r = 0; r < 4; ++r){
    int n = rowbase + quad * 4 + r;
    if (n < N) tp += Av[r] / Dv[r];
  }
  tp *= (1.0f / 16.0f);
  float tot = rsum256(tp, red4);
  if (t == 0) atomicAdd(out + b, tot);
}

} // anonymous namespace

extern "C" void kernel_launch(void* const* d_in, const int* in_sizes, int n_in,
                              void* d_out, int out_size, void* d_ws, size_t ws_size,
                              hipStream_t stream) {
  (void)in_sizes; (void)n_in; (void)out_size;
  const float* X      = (const float*)d_in[0];
  const float* spa_w1 = (const float*)d_in[1];
  const float* spa_b1 = (const float*)d_in[2];
  const float* spa_w2 = (const float*)d_in[3];
  const float* spa_b2 = (const float*)d_in[4];
  const float* tem_w1 = (const float*)d_in[5];
  const float* tem_b1 = (const float*)d_in[6];
  const float* tem_w2 = (const float*)d_in[7];
  const float* tem_b2 = (const float*)d_in[8];
  const float* sgnn_w = (const float*)d_in[9];
  const float* sgnn_b = (const float*)d_in[10];
  const float* tgnn_w = (const float*)d_in[11];
  const float* tgnn_b = (const float*)d_in[12];
  const float* q_w    = (const float*)d_in[13];
  const float* q_b    = (const float*)d_in[14];
  const float* k_w    = (const float*)d_in[15];
  const float* k_b    = (const float*)d_in[16];
  const float* v_w    = (const float*)d_in[17];
  const float* v_b    = (const float*)d_in[18];
  const float* fc_w   = (const float*)d_in[19];
  const float* fc_b   = (const float*)d_in[20];
  float* out = (float*)d_out;

  if (ws_size < (size_t)182714368) return;

  char* wsb = (char*)d_ws;
  float* H   = (float*)wsb;                      // fp32 H [0, 88MB)
  float* u1g = (float*)(wsb + 50331648);         // overlays dead-H region (H dead after cast)
  float* u2g = (float*)(wsb + 53215232);
  char*  Rb  = wsb + 88080384;
  float* Xf  = (float*)Rb;
  float* As  = (float*)(Rb + 20971520);
  float* At  = (float*)(Rb + 27525120);
  short* Hbf = (short*)Rb;                       // overlays dead Xf/As/At after ht
  char*  Pb  = Rb + 46137344;
  short* MT  = (short*)Pb;                       // 131072 B
  short* Rbf = (short*)(Pb + 131072);            // 180224 B (4 heads x 176 x 128 bf16)
  float* c1  = (float*)(Pb + 311296);
  float* c2  = (float*)(Pb + 313344);
  float* c3  = (float*)(Pb + 315392);
  float* c4  = (float*)(Pb + 315408);

  feat_kernel<<<BSZ * P / 4, 256, 0, stream>>>(X, Xf);
  cumnorm_kernel<<<BSZ, 256, 0, stream>>>(Xf);
  adjt_kernel<<<BSZ, 256, 0, stream>>>(Xf, tem_w1, tem_b1, tem_w2, tem_b2, At);
  adjs_kernel<<<BSZ, 256, 0, stream>>>(Xf, spa_w1, spa_b1, spa_w2, spa_b2, As);
  hs_kernel<<<BSZ, 256, 0, stream>>>(Xf, As, sgnn_w, sgnn_b, H);
  ht_kernel<<<BSZ, 256, 0, stream>>>(Xf, At, tgnn_w, tgnn_b, H);
  prep_kernel<<<dim3(NH, 11), 256, 0, stream>>>(q_w, q_b, k_w, k_b, v_w, v_b, fc_w,
                                                MT, Rbf, c1, c2, c3, c4);
  cast_kernel<<<BSZ, 256, 0, stream>>>(H, Hbf);          // H fp32 dead after this
  uprep_kernel<<<BSZ, 256, 0, stream>>>(Hbf, c1, c2, u1g, u2g);
  initout_kernel<<<4, 256, 0, stream>>>(out, fc_b, c4);
  attn_flash<<<dim3(BSZ, 11), 256, 0, stream>>>(Hbf, MT, Rbf, u1g, u2g, c3, out);
}

// Round 7
// 1249.385 us; speedup vs baseline: 1.2597x; 1.0627x over previous
//
#include <hip/hip_runtime.h>
#include <math.h>

namespace {

constexpr int BSZ  = 1024;
constexpr int P    = 128;
constexpr int HG   = 128;
constexpr int NH   = 4;
constexpr int N    = 168;     // P + IND
constexpr int NPAD = 176;     // padded token count (11 tiles of 16)

typedef short bf16x8 __attribute__((ext_vector_type(8)));
typedef float f32x4  __attribute__((ext_vector_type(4)));

__device__ __forceinline__ unsigned short f2bf(float x){
  union { float f; unsigned u; } v; v.f = x;
  unsigned r = (v.u + 0x7FFF + ((v.u >> 16) & 1)) >> 16;
  return (unsigned short)r;
}
__device__ __forceinline__ float bf2f(unsigned short b){
  union { unsigned u; float f; } v; v.u = ((unsigned)b) << 16;
  return v.f;
}

// ---------- wave (64-lane) butterfly reductions: result in ALL lanes ----------
__device__ __forceinline__ float wsum(float v){
  #pragma unroll
  for (int o = 1; o < 64; o <<= 1) v += __shfl_xor(v, o, 64);
  return v;
}
__device__ __forceinline__ float wmax(float v){
  #pragma unroll
  for (int o = 1; o < 64; o <<= 1) v = fmaxf(v, __shfl_xor(v, o, 64));
  return v;
}
__device__ __forceinline__ float wmin(float v){
  #pragma unroll
  for (int o = 1; o < 64; o <<= 1) v = fminf(v, __shfl_xor(v, o, 64));
  return v;
}
__device__ __forceinline__ float rsum256(float v, volatile float* red4){
  #pragma unroll
  for (int o = 32; o > 0; o >>= 1) v += __shfl_down(v, o, 64);
  __syncthreads();
  if ((threadIdx.x & 63) == 0) red4[threadIdx.x >> 6] = v;
  __syncthreads();
  return red4[0] + red4[1] + red4[2] + red4[3];
}

// ---------- K1: per-patch features, one WAVE per patch, no LDS, no barriers ----------
__global__ __launch_bounds__(256) void feat_kernel(const float* __restrict__ X,
                                                   float* __restrict__ Xf){
  const int wave = threadIdx.x >> 6, l = threadIdx.x & 63;
  const int pp = blockIdx.x * 4 + wave;          // patch id
  const float* xp = X + (size_t)pp * 128;
  const float x0 = xp[l];
  const float x1 = xp[l + 64];

  // ---- temporal ----
  float sum   = wsum(x0 + x1);
  float mean  = sum * (1.0f / 128.0f);
  float mx    = wmax(fmaxf(x0, x1));
  float mn    = wmin(fminf(x0, x1));
  float sumsq = wsum(fmaf(x0, x0, x1 * x1));
  float c0 = x0 - mean, c1_ = x1 - mean;
  float c0q = c0 * c0, c1q = c1_ * c1_;
  float m2 = wsum(c0q + c1q);
  float m3 = wsum(c0q * c0 + c1q * c1_);
  float m4 = wsum(c0q * c0q + c1q * c1q);
  float var = m2 * (1.0f / 127.0f);
  float sd  = sqrtf(var);
  float rms = sqrtf(sumsq * (1.0f / 128.0f));
  float ex0 = expf(x0 - mx), ex1 = expf(x1 - mx);
  float Z   = wsum(ex0 + ex1);
  float SxE = wsum(fmaf(ex0, x0, ex1 * x1));
  float ent = (mx + logf(Z)) - SxE / Z;
  const float lo = (float)(-1.0 + 1e-7), hi = (float)(1.0 - 1e-7);
  float a0 = asinf(fminf(fmaxf(x0, lo), hi));
  float a1 = asinf(fminf(fmaxf(x1, lo), hi));
  float amean = wsum(a0 + a1) * (1.0f / 128.0f);
  float ad0 = a0 - amean, ad1 = a1 - amean;
  float std_asin = sqrtf(wsum(fmaf(ad0, ad0, ad1 * ad1)) * (1.0f / 127.0f));
  float b0 = atanf(x0), b1v = atanf(x1);
  float bmean = wsum(b0 + b1v) * (1.0f / 128.0f);
  float bd0 = b0 - bmean, bd1 = b1v - bmean;
  float std_atan = sqrtf(wsum(fmaf(bd0, bd0, bd1 * bd1)) * (1.0f / 127.0f));
  float kurt = (m4 * (1.0f / 128.0f)) / (sd * sd * sd * sd) - 3.0f;
  float skew = (m3 * (1.0f / 128.0f)) / (sd * sd * sd);

  // ---- DFT: lane l computes bin l via rotation recurrence (64 folded steps) ----
  const float sign = (l & 1) ? -1.0f : 1.0f;
  float sC, cC;
  __sincosf((float)l * 0.049087385212340517f, &sC, &cC);   // 2*pi*l/128
  const float c1r = cC, s1r = -sC;
  const int x0i = __float_as_int(x0), x1i = __float_as_int(x1);
  float re = 0.f, im = 0.f;
  float wc = 1.f, ws = 0.f;
  #pragma unroll 8
  for (int tt = 0; tt < 32; ++tt){
    float s0v = __int_as_float(__builtin_amdgcn_readlane(x0i, tt));
    float s1v = __int_as_float(__builtin_amdgcn_readlane(x1i, tt));
    float se = fmaf(sign, s1v, s0v);
    re = fmaf(se, wc, re);
    im = fmaf(se, ws, im);
    float t1 = ws * s1r, t2 = ws * c1r;
    float nwc = fmaf(wc, c1r, -t1);
    ws = fmaf(wc, s1r, t2);
    wc = nwc;
  }
  { // exact reseed at tt=32: w = e^{-i*pi*l/2}
    int lm = l & 3;
    wc = (lm == 0) ? 1.f : (lm == 2) ? -1.f : 0.f;
    ws = (lm == 1) ? -1.f : (lm == 3) ? 1.f : 0.f;
  }
  #pragma unroll 8
  for (int tt = 32; tt < 64; ++tt){
    float s0v = __int_as_float(__builtin_amdgcn_readlane(x0i, tt));
    float s1v = __int_as_float(__builtin_amdgcn_readlane(x1i, tt));
    float se = fmaf(sign, s1v, s0v);
    re = fmaf(se, wc, re);
    im = fmaf(se, ws, im);
    float t1 = ws * s1r, t2 = ws * c1r;
    float nwc = fmaf(wc, c1r, -t1);
    ws = fmaf(wc, s1r, t2);
    wc = nwc;
  }
  float psd = fmaf(re, re, im * im) * 0.0078125f;          // bins 0..63 (lane l)
  float re64 = wsum(sign * (x0 + x1));                     // bin 64
  float psd64 = re64 * re64 * 0.0078125f;

  const float mult = (l == 0) ? 1.f : 2.f;
  float psum = wsum(psd * mult) + psd64;
  float p2   = wsum(psd * psd * mult) + psd64 * psd64;
  float vm   = wmax(psd);
  float maxp = fmaxf(vm, psd64);
  float meanfreq = (-0.5f * psd64) / psum;
  float pbw = sqrtf(p2 / psum);
  float cand = (psd == vm) ? (float)l : 1e9f;              // first-index argmax
  float lminf = wmin(cand);
  float fmaxv = (psd64 > vm) ? -0.5f : lminf * (1.0f / 128.0f);
  float maxamp = sqrtf(maxp * 128.0f);

  // ---- median (stable rank 64 of 128, multiplicity-aware ballot rank) ----
  float med = -0.5f;
  for (int kt = 0; kt < 64; ++kt){
    float vt = __int_as_float(__builtin_amdgcn_readlane(__float_as_int(psd), kt));
    unsigned long long mask = __ballot(psd < vt);
    int less = 2 * __popcll(mask) - (int)(mask & 1ull) + ((psd64 < vt) ? 1 : 0);
    if (less == 64) med = (float)kt * (1.0f / 128.0f);
    else if (less == 63 && kt >= 1) med = -(float)kt * (1.0f / 128.0f);
  }
  {
    unsigned long long mask = __ballot(psd < psd64);
    int less = 2 * __popcll(mask) - (int)(mask & 1ull);
    if (less == 64) med = -0.5f;
  }

  if (l == 0){
    float* o = Xf + (size_t)pp * 40;
    o[0]  = mx;  o[1]  = mn;  o[2]  = sd;   o[3]  = rms; o[4]  = mean;
    o[5]  = mx - mn;  o[6] = var;  o[7] = ent; o[8] = std_asin; o[9] = std_atan;
    o[10] = kurt; o[11] = skew;
    o[12] = meanfreq;
    o[13] = med;
    o[14] = psum;
    o[15] = 1.0f;
    o[16] = pbw;
    o[17] = maxp;
    o[18] = maxamp;
    o[19] = fmaxv;
  }
}

// ---------- K2: cumsum feature + per-sample normalization ----------
__global__ __launch_bounds__(256) void cumnorm_kernel(float* __restrict__ Xf){
  const int b = blockIdx.x, t = threadIdx.x;
  __shared__ float arr[128 * 40];
  __shared__ float red4[4];
  float* base = Xf + b * 5120;
  for (int idx = t; idx < 128 * 20; idx += 256){
    int p = idx / 20, c = idx - p * 20;
    arr[p * 40 + c] = base[p * 40 + c];
  }
  __syncthreads();
  if (t < 20){
    float acc = 0.f;
    for (int p = 0; p < 128; ++p){
      acc += arr[p * 40 + t];
      arr[p * 40 + 20 + t] = acc / sqrtf(fmaxf(fabsf(acc), 1e-12f));
    }
  }
  __syncthreads();
  float pa = 0.f;
  for (int idx = t; idx < 5120; idx += 256){ float v = arr[idx]; pa = fmaf(v, v, pa); }
  float nrm = sqrtf(rsum256(pa, red4));
  for (int idx = t; idx < 5120; idx += 256) base[idx] = arr[idx] / nrm;
}

// ---------- K3: A_t (register-tiled fp32; K-order per output unchanged) ----------
__global__ __launch_bounds__(256) void adjt_kernel(const float* __restrict__ Xf,
    const float* __restrict__ w1, const float* __restrict__ b1,
    const float* __restrict__ w2, const float* __restrict__ b2,
    float* __restrict__ At){
  const int b = blockIdx.x, t = threadIdx.x;
  __shared__ float xf[5120];          // stride 40
  __shared__ float T[128 * 64];
  const float* src = Xf + b * 5120;
  for (int idx = t; idx < 1280; idx += 256)
    *((float4*)xf + idx) = *((const float4*)src + idx);
  __syncthreads();

  // T1[i][k] = tanh(b1[k] + sum_c xf[i][c]*w1[c][k]); tile 8i x 4k per thread
  {
    const int k0 = (t & 15) * 4, i0 = (t >> 4) * 8;
    float4 bv = *(const float4*)&b1[k0];
    float acc[8][4];
    #pragma unroll
    for (int di = 0; di < 8; ++di){ acc[di][0]=bv.x; acc[di][1]=bv.y; acc[di][2]=bv.z; acc[di][3]=bv.w; }
    for (int c = 0; c < 40; ++c){
      float4 wv = *(const float4*)&w1[c * 64 + k0];
      #pragma unroll
      for (int di = 0; di < 8; ++di){
        float xv = xf[(i0 + di) * 40 + c];
        acc[di][0] = fmaf(xv, wv.x, acc[di][0]);
        acc[di][1] = fmaf(xv, wv.y, acc[di][1]);
        acc[di][2] = fmaf(xv, wv.z, acc[di][2]);
        acc[di][3] = fmaf(xv, wv.w, acc[di][3]);
      }
    }
    #pragma unroll
    for (int di = 0; di < 8; ++di){
      float4 o;
      o.x = tanhf(acc[di][0]); o.y = tanhf(acc[di][1]);
      o.z = tanhf(acc[di][2]); o.w = tanhf(acc[di][3]);
      *(float4*)&T[(i0 + di) * 64 + k0] = o;
    }
  }
  __syncthreads();

  // A_t[i][j] = b2[j] + sum_k T[i][k]*w2[k][j]; tile 16i x 4j per thread
  {
    const int j0 = (t & 31) * 4, i0 = (t >> 5) * 16;
    float4 bv = *(const float4*)&b2[j0];
    float acc[16][4];
    #pragma unroll
    for (int di = 0; di < 16; ++di){ acc[di][0]=bv.x; acc[di][1]=bv.y; acc[di][2]=bv.z; acc[di][3]=bv.w; }
    for (int k = 0; k < 64; ++k){
      float4 wv = *(const float4*)&w2[k * 128 + j0];
      #pragma unroll
      for (int di = 0; di < 16; ++di){
        float tv = T[(i0 + di) * 64 + k];
        acc[di][0] = fmaf(tv, wv.x, acc[di][0]);
        acc[di][1] = fmaf(tv, wv.y, acc[di][1]);
        acc[di][2] = fmaf(tv, wv.z, acc[di][2]);
        acc[di][3] = fmaf(tv, wv.w, acc[di][3]);
      }
    }
    float* dst = At + (size_t)b * 16384;
    #pragma unroll
    for (int di = 0; di < 16; ++di)
      *(float4*)&dst[(i0 + di) * 128 + j0] = *(float4*)acc[di];
  }
}

// ---------- K4: A_s ----------
__global__ __launch_bounds__(256) void adjs_kernel(const float* __restrict__ Xf,
    const float* __restrict__ w1, const float* __restrict__ b1,
    const float* __restrict__ w2, const float* __restrict__ b2,
    float* __restrict__ As){
  const int b = blockIdx.x, t = threadIdx.x;
  __shared__ float xf[5120];
  __shared__ float T2[40 * 64];
  const float* src = Xf + b * 5120;
  for (int idx = t; idx < 1280; idx += 256)
    *((float4*)xf + idx) = *((const float4*)src + idx);
  __syncthreads();
  for (int idx = t; idx < 40 * 64; idx += 256){
    int i = idx >> 6, k = idx & 63;
    float acc = b1[k];
    for (int p = 0; p < 128; ++p) acc = fmaf(xf[p * 40 + i], w1[p * 64 + k], acc);
    T2[idx] = tanhf(acc);
  }
  __syncthreads();
  float* dst = As + b * 1600;
  for (int idx = t; idx < 1600; idx += 256){
    int i = idx / 40, j = idx - i * 40;
    float acc = b2[j];
    #pragma unroll 8
    for (int k = 0; k < 64; ++k) acc = fmaf(T2[i * 64 + k], w2[k * 40 + j], acc);
    dst[idx] = acc;
  }
}

// ---------- K5: H_s (register-tiled) ----------
__global__ __launch_bounds__(256) void hs_kernel(const float* __restrict__ Xf,
    const float* __restrict__ As_g, const float* __restrict__ w, const float* __restrict__ bias,
    float* __restrict__ H){
  const int b = blockIdx.x, t = threadIdx.x;
  __shared__ float xf[5120];          // stride 40
  __shared__ float As[1600];
  __shared__ float M[40 * 128];
  const float* src = Xf + b * 5120;
  for (int idx = t; idx < 1280; idx += 256)
    *((float4*)xf + idx) = *((const float4*)src + idx);
  for (int idx = t; idx < 400; idx += 256)
    *((float4*)As + idx) = *((const float4*)(As_g + b * 1600) + idx);
  __syncthreads();

  // M[i][p] = sum_m As[i][m] * xf[p][m]; tile 5i x 4p, m in float4 steps
  {
    const int p0 = (t & 31) * 4, i0 = (t >> 5) * 5;
    float acc[5][4];
    #pragma unroll
    for (int di = 0; di < 5; ++di)
      #pragma unroll
      for (int dp = 0; dp < 4; ++dp) acc[di][dp] = 0.f;
    for (int m = 0; m < 40; m += 4){
      float4 a4[5], x4[4];
      #pragma unroll
      for (int di = 0; di < 5; ++di) a4[di] = *(const float4*)&As[(i0 + di) * 40 + m];
      #pragma unroll
      for (int dp = 0; dp < 4; ++dp) x4[dp] = *(const float4*)&xf[(p0 + dp) * 40 + m];
      #pragma unroll
      for (int dm = 0; dm < 4; ++dm)
        #pragma unroll
        for (int di = 0; di < 5; ++di){
          float av = (&a4[di].x)[dm];
          #pragma unroll
          for (int dp = 0; dp < 4; ++dp)
            acc[di][dp] = fmaf(av, (&x4[dp].x)[dm], acc[di][dp]);
        }
    }
    #pragma unroll
    for (int di = 0; di < 5; ++di)
      *(float4*)&M[(i0 + di) * 128 + p0] = *(float4*)acc[di];
  }
  __syncthreads();

  // H_s[i][j] = leaky(bias[j] + sum_p M[i][p]*w[p][j]); tile 5i x 4j
  {
    const int j0 = (t & 31) * 4, i0 = (t >> 5) * 5;
    float4 bv = *(const float4*)&bias[j0];
    float acc[5][4];
    #pragma unroll
    for (int di = 0; di < 5; ++di){ acc[di][0]=bv.x; acc[di][1]=bv.y; acc[di][2]=bv.z; acc[di][3]=bv.w; }
    for (int p = 0; p < 128; ++p){
      float4 wv = *(const float4*)&w[p * 128 + j0];
      #pragma unroll
      for (int di = 0; di < 5; ++di){
        float mv = M[(i0 + di) * 128 + p];
        acc[di][0] = fmaf(mv, wv.x, acc[di][0]);
        acc[di][1] = fmaf(mv, wv.y, acc[di][1]);
        acc[di][2] = fmaf(mv, wv.z, acc[di][2]);
        acc[di][3] = fmaf(mv, wv.w, acc[di][3]);
      }
    }
    float* dst = H + (size_t)b * (N * HG);
    #pragma unroll
    for (int di = 0; di < 5; ++di){
      float4 o;
      o.x = (acc[di][0] >= 0.f) ? acc[di][0] : 0.01f * acc[di][0];
      o.y = (acc[di][1] >= 0.f) ? acc[di][1] : 0.01f * acc[di][1];
      o.z = (acc[di][2] >= 0.f) ? acc[di][2] : 0.01f * acc[di][2];
      o.w = (acc[di][3] >= 0.f) ? acc[di][3] : 0.01f * acc[di][3];
      *(float4*)&dst[(i0 + di) * 128 + j0] = o;
    }
  }
}

// ---------- K6: H_t (register-tiled) ----------
__global__ __launch_bounds__(256) void ht_kernel(const float* __restrict__ Xf,
    const float* __restrict__ At_g, const float* __restrict__ w, const float* __restrict__ bias,
    float* __restrict__ H){
  const int b = blockIdx.x, t = threadIdx.x;
  __shared__ float xf[5120];          // stride 40
  __shared__ float M2[128 * 40];
  const float* src = Xf + b * 5120;
  for (int idx = t; idx < 1280; idx += 256)
    *((float4*)xf + idx) = *((const float4*)src + idx);
  __syncthreads();

  // M2[i][c] = sum_m At[i][m] * xf[m][c]; tile 4i x 5c, m in float4 steps
  {
    const int c0 = (t & 7) * 5, i0 = (t >> 3) * 4;
    const float* At = At_g + (size_t)b * 16384;
    float acc[4][5];
    #pragma unroll
    for (int di = 0; di < 4; ++di)
      #pragma unroll
      for (int dc = 0; dc < 5; ++dc) acc[di][dc] = 0.f;
    for (int m = 0; m < 128; m += 4){
      float4 a4[4];
      #pragma unroll
      for (int di = 0; di < 4; ++di) a4[di] = *(const float4*)&At[(i0 + di) * 128 + m];
      #pragma unroll
      for (int dm = 0; dm < 4; ++dm){
        float xv[5];
        #pragma unroll
        for (int dc = 0; dc < 5; ++dc) xv[dc] = xf[(m + dm) * 40 + c0 + dc];
        #pragma unroll
        for (int di = 0; di < 4; ++di){
          float av = (&a4[di].x)[dm];
          #pragma unroll
          for (int dc = 0; dc < 5; ++dc)
            acc[di][dc] = fmaf(av, xv[dc], acc[di][dc]);
        }
      }
    }
    #pragma unroll
    for (int di = 0; di < 4; ++di)
      #pragma unroll
      for (int dc = 0; dc < 5; ++dc)
        M2[(i0 + di) * 40 + c0 + dc] = acc[di][dc];
  }
  __syncthreads();

  // H_t[i][j] = leaky(bias[j] + sum_c M2[i][c]*w[c][j]); tile 16i x 4j
  {
    const int j0 = (t & 31) * 4, i0 = (t >> 5) * 16;
    float4 bv = *(const float4*)&bias[j0];
    float acc[16][4];
    #pragma unroll
    for (int di = 0; di < 16; ++di){ acc[di][0]=bv.x; acc[di][1]=bv.y; acc[di][2]=bv.z; acc[di][3]=bv.w; }
    for (int c = 0; c < 40; ++c){
      float4 wv = *(const float4*)&w[c * 128 + j0];
      #pragma unroll
      for (int di = 0; di < 16; ++di){
        float mv = M2[(i0 + di) * 40 + c];
        acc[di][0] = fmaf(mv, wv.x, acc[di][0]);
        acc[di][1] = fmaf(mv, wv.y, acc[di][1]);
        acc[di][2] = fmaf(mv, wv.z, acc[di][2]);
        acc[di][3] = fmaf(mv, wv.w, acc[di][3]);
      }
    }
    float* dst = H + (size_t)b * (N * HG) + 40 * 128;
    #pragma unroll
    for (int di = 0; di < 16; ++di){
      float4 o;
      o.x = (acc[di][0] >= 0.f) ? acc[di][0] : 0.01f * acc[di][0];
      o.y = (acc[di][1] >= 0.f) ? acc[di][1] : 0.01f * acc[di][1];
      o.z = (acc[di][2] >= 0.f) ? acc[di][2] : 0.01f * acc[di][2];
      o.w = (acc[di][3] >= 0.f) ? acc[di][3] : 0.01f * acc[di][3];
      *(float4*)&dst[(i0 + di) * 128 + j0] = o;
    }
  }
}

// out[b] = fc_b + sum_h c4[h]  (c4 = vb-term collapsed: rows of P sum to 1)
__global__ void initout_kernel(float* __restrict__ out, const float* __restrict__ fcb,
                               const float* __restrict__ c4){
  int i = blockIdx.x * 256 + threadIdx.x;
  float base = fcb[0] + c4[0] + c4[1] + c4[2] + c4[3];
  if (i < BSZ) out[i] = base;
}

// ---------- prep: per-head M^T, R = fcw·Wv^T, c1/c2/c3/c4; grid (NH, 11) ----------
// R[h][n][d] = sum_e fcw[n*512+h*128+e] * vw[h][d][e]  (b-independent!)
// c4[h] = sum_{n<168} sum_e vb[h][e] * fcw[n*512+h*128+e]
__global__ __launch_bounds__(256) void prep_kernel(
    const float* __restrict__ qw, const float* __restrict__ qb,
    const float* __restrict__ kw, const float* __restrict__ kb,
    const float* __restrict__ vw, const float* __restrict__ vb,
    const float* __restrict__ fcw,
    short* __restrict__ MT, short* __restrict__ Rbf,
    float* __restrict__ c1, float* __restrict__ c2,
    float* __restrict__ c3, float* __restrict__ c4){
  const int h = blockIdx.x, sl = blockIdx.y, t = threadIdx.x;
  const float* Q = qw + h * 16384;
  const float* K = kw + h * 16384;
  const float* V = vw + h * 16384;
  if (sl < 8){
    for (int idx = t; idx < 2048; idx += 256){
      int j = sl * 16 + (idx >> 7), d = idx & 127;
      float acc = 0.f;
      for (int e = 0; e < 128; ++e) acc = fmaf(Q[d * 128 + e], K[j * 128 + e], acc);
      MT[h * 16384 + j * 128 + d] = (short)f2bf(acc);     // MT[j][d] = M[d][j]
    }
    if (t < 16){
      int r = sl * 16 + t;
      float a = 0.f, bsum = 0.f;
      for (int e = 0; e < 128; ++e){
        a    = fmaf(Q[r * 128 + e], kb[h * 128 + e], a);
        bsum = fmaf(K[r * 128 + e], qb[h * 128 + e], bsum);
      }
      c1[h * 128 + r] = a;
      c2[h * 128 + r] = bsum;
    }
  }
  // R rows n in [sl*16, sl*16+16); zero-pad n >= 168
  for (int idx = t; idx < 2048; idx += 256){
    int n = sl * 16 + (idx >> 7), d = idx & 127;
    float acc = 0.f;
    if (n < N){
      const float* fr = fcw + n * 512 + h * 128;
      const float* vr = V + d * 128;
      for (int e = 0; e < 128; ++e) acc = fmaf(fr[e], vr[e], acc);
    }
    Rbf[h * 22528 + n * 128 + d] = (short)f2bf(acc);
  }
  if (sl == 0){
    if (t == 0){
      float a = 0.f;
      for (int e = 0; e < 128; ++e) a = fmaf(qb[h * 128 + e], kb[h * 128 + e], a);
      c3[h] = a;
    }
    if (t >= 64 && t < 128){                  // wave 1: c4 reduction
      int l = t - 64;
      float part = 0.f;
      for (int i = l; i < N * 128; i += 64){
        int n = i >> 7, e = i & 127;
        part = fmaf(fcw[n * 512 + h * 128 + e], vb[h * 128 + e], part);
      }
      part = wsum(part);
      if (l == 0) c4[h] = part;
    }
  }
}

// ---------- cast H -> bf16 with zero-padded rows 168..175 ----------
__global__ __launch_bounds__(256) void cast_kernel(const float* __restrict__ H,
                                                   short* __restrict__ Hbf){
  const int b = blockIdx.x;
  for (int idx = threadIdx.x; idx < NPAD * 128; idx += 256){
    int n = idx >> 7, d = idx & 127;
    float v = (n < N) ? H[((size_t)b * N + n) * 128 + d] : 0.f;
    Hbf[(size_t)b * NPAD * 128 + idx] = (short)f2bf(v);
  }
}

// ---------- u1/u2 precompute: u1[n]=H[n]·c1, u2[n]=H[n]·c2 per (b,h) ----------
__global__ __launch_bounds__(256) void uprep_kernel(const short* __restrict__ Hbf,
    const float* __restrict__ c1, const float* __restrict__ c2,
    float* __restrict__ u1g, float* __restrict__ u2g){
  const int b = blockIdx.x, t = threadIdx.x;
  for (int idx = t; idx < 176 * 4; idx += 256){
    int n = idx >> 2, h = idx & 3;
    const bf16x8* rp = (const bf16x8*)(Hbf + (size_t)b * NPAD * 128 + (size_t)n * 128);
    const float* C1 = c1 + h * 128;
    const float* C2 = c2 + h * 128;
    float a1 = 0.f, a2 = 0.f;
    for (int kk = 0; kk < 16; ++kk){
      bf16x8 v = rp[kk];
      #pragma unroll
      for (int j = 0; j < 8; ++j){
        float hv = bf2f((unsigned short)v[j]);
        a1 = fmaf(hv, C1[kk * 8 + j], a1);
        a2 = fmaf(hv, C2[kk * 8 + j], a2);
      }
    }
    u1g[(size_t)(b * 4 + h) * 176 + n] = a1;
    u2g[(size_t)(b * 4 + h) * 176 + n] = a2;
  }
}

// ---------- attention, flash-style, 16-wave block: grid (b) ----------
// One cooperative XOR-swizzled LDS stage of the whole Hb panel (45KB) per block,
// ONE barrier, then 16 waves run 44 independent (zt,h) flash tasks (2-3 each):
// Phase A (T=H@M from LDS, private Tsh slice), 11 m-tile fused S/G MFMA with
// per-lane online softmax — all A/B operands from LDS. Global left: MTh (L2-hot),
// Rh, u1/u2. Hb HBM traffic: once per b (was ~44x). Swizzle both-sides (#21):
// stage writes group g^(row&15); reads use (kk*4+quad)^l15 (row&15==l15).
__global__ __launch_bounds__(1024, 4) void attn_flash(
    const short* __restrict__ Hbf, const short* __restrict__ MT,
    const short* __restrict__ Rbf,
    const float* __restrict__ u1g, const float* __restrict__ u2g,
    const float* __restrict__ c3g, float* __restrict__ out){
  const int b = blockIdx.x;
  const int t = threadIdx.x;
  const int wv = t >> 6, l = t & 63, quad = l >> 4, l15 = l & 15;
  const int h = wv & 3;

  __shared__ __align__(16) short Hsh[NPAD * 128];     // 45KB, swizzled
  __shared__ __align__(16) short Tsh[16 * 2048];      // 64KB, 4KB/wave private
  __shared__ float red16[16];

  const short* Hb = Hbf + (size_t)b * NPAD * 128;

  // ---- cooperative stage: 2816 x 16B units, coalesced global, swizzled LDS ----
  #pragma unroll
  for (int i = 0; i < 3; ++i){
    int idx = t + i * 1024;
    if (idx < 2816){
      int row = idx >> 4, g = idx & 15;
      bf16x8 v = *(const bf16x8*)(Hb + row * 128 + g * 8);
      *(bf16x8*)(Hsh + row * 128 + ((g ^ (row & 15)) * 8)) = v;
    }
  }
  __syncthreads();

  const short* MTh = MT + h * 16384;
  const short* Rh  = Rbf + h * 22528;
  const float c3v = c3g[h];
  const float inv = 0.08838834764831845f;   // 1/sqrt(128)
  const float* u1p = u1g + (size_t)(b * 4 + h) * 176;
  const float* u2p = u2g + (size_t)(b * 4 + h) * 176;
  short* Tw = Tsh + wv * 2048;

  float tp = 0.f;
  #pragma unroll
  for (int ti = 0; ti < 3; ++ti){
    const int zt = (wv >> 2) + ti * 4;
    if (zt < 11){                                  // wave-uniform guard
      const int rowbase = zt * 16;

      // A-frags (H rows, from LDS) and R-frags (global, L2-hot)
      bf16x8 HA[4], RA[4];
      #pragma unroll
      for (int kk = 0; kk < 4; ++kk){
        HA[kk] = *(const bf16x8*)(Hsh + (rowbase + l15) * 128 + (((kk * 4 + quad) ^ l15) * 8));
        RA[kk] = *(const bf16x8*)(Rh + (rowbase + l15) * 128 + kk * 32 + quad * 8);
      }
      float u1v[4];
      #pragma unroll
      for (int r = 0; r < 4; ++r) u1v[r] = u1p[rowbase + quad * 4 + r];

      // ---- Phase A: T = H_chunk @ M -> private LDS slice (XOR-swizzled) ----
      #pragma unroll
      for (int jt = 0; jt < 8; ++jt){
        const int j0 = jt * 16;
        f32x4 acc = {0.f, 0.f, 0.f, 0.f};
        #pragma unroll
        for (int kk = 0; kk < 4; ++kk){
          bf16x8 Bv = *(const bf16x8*)(MTh + (j0 + l15) * 128 + kk * 32 + quad * 8);
          acc = __builtin_amdgcn_mfma_f32_16x16x32_bf16(HA[kk], Bv, acc, 0, 0, 0);
        }
        const int jcol = j0 + l15, ch = jcol >> 3;
        #pragma unroll
        for (int r = 0; r < 4; ++r){
          int row = quad * 4 + r;
          Tw[row * 128 + ((ch ^ row) << 3) + (jcol & 7)] = (short)f2bf(acc[r]);
        }
      }
      // no barrier: same-wave DS ops are ordered

      // ---- Phase BG + per-lane online softmax over 11 m-tiles ----
      float Mx[4], Av[4], Dv[4];
      #pragma unroll
      for (int r = 0; r < 4; ++r){ Mx[r] = -1e30f; Av[r] = 0.f; Dv[r] = 0.f; }

      #pragma unroll
      for (int mt = 0; mt < 11; ++mt){
        const int m0 = mt * 16;
        bf16x8 Bv[4];
        #pragma unroll
        for (int kk = 0; kk < 4; ++kk)
          Bv[kk] = *(const bf16x8*)(Hsh + (m0 + l15) * 128 + (((kk * 4 + quad) ^ l15) * 8));
        const float u2v = u2p[m0 + l15];
        f32x4 acc = {0.f, 0.f, 0.f, 0.f};
        f32x4 g   = {0.f, 0.f, 0.f, 0.f};
        #pragma unroll
        for (int kk = 0; kk < 4; ++kk){
          bf16x8 A = *(const bf16x8*)(Tw + l15 * 128 + (((kk * 4 + quad) ^ l15) << 3));
          acc = __builtin_amdgcn_mfma_f32_16x16x32_bf16(A, Bv[kk], acc, 0, 0, 0);
          g   = __builtin_amdgcn_mfma_f32_16x16x32_bf16(RA[kk], Bv[kk], g, 0, 0, 0);
        }
        const bool padcol = (mt == 10) && (l15 >= 8);     // cols 168..175 masked
        #pragma unroll
        for (int r = 0; r < 4; ++r){
          float s = padcol ? -1e30f : (acc[r] + u1v[r] + u2v + c3v) * inv;
          float Mn = fmaxf(Mx[r], s);
          float ea = __expf(Mx[r] - Mn);
          float eb = __expf(s - Mn);
          Av[r] = fmaf(Av[r], ea, eb * g[r]);
          Dv[r] = fmaf(Dv[r], ea, eb);
          Mx[r] = Mn;
        }
      }

      // ---- merge (M,A,D) across the 16 l15 lanes (stays within quad) ----
      #pragma unroll
      for (int r = 0; r < 4; ++r){
        #pragma unroll
        for (int o = 1; o < 16; o <<= 1){
          float M2 = __shfl_xor(Mx[r], o, 64);
          float A2 = __shfl_xor(Av[r], o, 64);
          float D2 = __shfl_xor(Dv[r], o, 64);
          float Mn = fmaxf(Mx[r], M2);
          float ea = __expf(Mx[r] - Mn);
          float eb = __expf(M2 - Mn);
          Av[r] = fmaf(Av[r], ea, A2 * eb);
          Dv[r] = fmaf(Dv[r], ea, D2 * eb);
          Mx[r] = Mn;
        }
      }

      // ---- per-row A/D, replicated over 16 lanes -> scale by 1/16 ----
      #pragma unroll
      for (int r = 0; r < 4; ++r){
        int n = rowbase + quad * 4 + r;
        if (n < N) tp += Av[r] / Dv[r];
      }
    }
  }
  tp *= (1.0f / 16.0f);

  // ---- block reduction over 16 waves ----
  #pragma unroll
  for (int o = 32; o > 0; o >>= 1) tp += __shfl_down(tp, o, 64);
  if (l == 0) red16[wv] = tp;
  __syncthreads();
  if (t == 0){
    float s = 0.f;
    #pragma unroll
    for (int i = 0; i < 16; ++i) s += red16[i];
    atomicAdd(out + b, s);
  }
}

} // anonymous namespace

extern "C" void kernel_launch(void* const* d_in, const int* in_sizes, int n_in,
                              void* d_out, int out_size, void* d_ws, size_t ws_size,
                              hipStream_t stream) {
  (void)in_sizes; (void)n_in; (void)out_size;
  const float* X      = (const float*)d_in[0];
  const float* spa_w1 = (const float*)d_in[1];
  const float* spa_b1 = (const float*)d_in[2];
  const float* spa_w2 = (const float*)d_in[3];
  const float* spa_b2 = (const float*)d_in[4];
  const float* tem_w1 = (const float*)d_in[5];
  const float* tem_b1 = (const float*)d_in[6];
  const float* tem_w2 = (const float*)d_in[7];
  const float* tem_b2 = (const float*)d_in[8];
  const float* sgnn_w = (const float*)d_in[9];
  const float* sgnn_b = (const float*)d_in[10];
  const float* tgnn_w = (const float*)d_in[11];
  const float* tgnn_b = (const float*)d_in[12];
  const float* q_w    = (const float*)d_in[13];
  const float* q_b    = (const float*)d_in[14];
  const float* k_w    = (const float*)d_in[15];
  const float* k_b    = (const float*)d_in[16];
  const float* v_w    = (const float*)d_in[17];
  const float* v_b    = (const float*)d_in[18];
  const float* fc_w   = (const float*)d_in[19];
  const float* fc_b   = (const float*)d_in[20];
  float* out = (float*)d_out;

  if (ws_size < (size_t)182714368) return;

  char* wsb = (char*)d_ws;
  float* H   = (float*)wsb;                      // fp32 H [0, 88MB)
  float* u1g = (float*)(wsb + 50331648);         // overlays dead-H region (H dead after cast)
  float* u2g = (float*)(wsb + 53215232);
  char*  Rb  = wsb + 88080384;
  float* Xf  = (float*)Rb;
  float* As  = (float*)(Rb + 20971520);
  float* At  = (float*)(Rb + 27525120);
  short* Hbf = (short*)Rb;                       // overlays dead Xf/As/At after ht
  char*  Pb  = Rb + 46137344;
  short* MT  = (short*)Pb;                       // 131072 B
  short* Rbf = (short*)(Pb + 131072);            // 180224 B (4 heads x 176 x 128 bf16)
  float* c1  = (float*)(Pb + 311296);
  float* c2  = (float*)(Pb + 313344);
  float* c3  = (float*)(Pb + 315392);
  float* c4  = (float*)(Pb + 315408);

  feat_kernel<<<BSZ * P / 4, 256, 0, stream>>>(X, Xf);
  cumnorm_kernel<<<BSZ, 256, 0, stream>>>(Xf);
  adjt_kernel<<<BSZ, 256, 0, stream>>>(Xf, tem_w1, tem_b1, tem_w2, tem_b2, At);
  adjs_kernel<<<BSZ, 256, 0, stream>>>(Xf, spa_w1, spa_b1, spa_w2, spa_b2, As);
  hs_kernel<<<BSZ, 256, 0, stream>>>(Xf, As, sgnn_w, sgnn_b, H);
  ht_kernel<<<BSZ, 256, 0, stream>>>(Xf, At, tgnn_w, tgnn_b, H);
  prep_kernel<<<dim3(NH, 11), 256, 0, stream>>>(q_w, q_b, k_w, k_b, v_w, v_b, fc_w,
                                                MT, Rbf, c1, c2, c3, c4);
  cast_kernel<<<BSZ, 256, 0, stream>>>(H, Hbf);          // H fp32 dead after this
  uprep_kernel<<<BSZ, 256, 0, stream>>>(Hbf, c1, c2, u1g, u2g);
  initout_kernel<<<4, 256, 0, stream>>>(out, fc_b, c4);
  attn_flash<<<dim3(BSZ), 1024, 0, stream>>>(Hbf, MT, Rbf, u1g, u2g, c3, out);
}